// Round 1
// baseline (590.461 us; speedup 1.0000x reference)
//
#include <hip/hip_runtime.h>
#include <hip/hip_cooperative_groups.h>

namespace cg = cooperative_groups;

// ---------------------------------------------------------------------------
// PEPS 4x5, D=4, P=2, depth-5 gate sweeps, 64-point gather.
// SINGLE cooperative kernel: build_cols -> small -> t012 -> psi0 -> 5x(P1,P2),
// grid.sync() between phases (replaces 13 kernel-launch boundaries).
// Gate layout: psi idx = c3<<16 | c4<<12 | c0<<8 | c1<<4 | c2.
// ---------------------------------------------------------------------------

#define PAD(i) ((i) + (((i) >> 4) << 2))   // +4 floats per 16 -> LDS bank spread
#define PIDX(i,j,p,u,d,l,r) (((((((i)*5+(j))*2+(p))*4+(u))*4+(d))*4+(l))*4+(r))

// workspace float offsets
static constexpr int COL0  = 0;                    // [16][256]
static constexpr int COL1  = 4096;                 // [16][256][256]
static constexpr int COL2  = COL1 + 1048576;
static constexpr int COL3  = COL2 + 1048576;
static constexpr int COL4  = COL3 + 1048576;       // [16][256]
static constexpr int M01TO = COL4 + 4096;          // [c01=256][R2=256]
static constexpr int M34TO = M01TO + 65536;        // [L3=256][c34=256]
static constexpr int T12TO = M34TO + 65536;        // [c2=16][c01=256][R3=256]
static constexpr int PSIO  = T12TO + 1048576;      // [2^20] gate layout

// ---------------- register-level 2-qubit gate ------------------------------
template <int NB, int HI, int LO>
__device__ __forceinline__ void gate2(float* x, const float* __restrict__ g) {
  constexpr int H = 1 << HI, L = 1 << LO, N = 1 << NB;
#pragma unroll
  for (int o = 0; o < N; ++o) {
    if (o & (H | L)) continue;
    float v0 = x[o], v1 = x[o + L], v2 = x[o + H], v3 = x[o + H + L];
    x[o]         = g[0]  * v0 + g[1]  * v1 + g[2]  * v2 + g[3]  * v3;
    x[o + L]     = g[4]  * v0 + g[5]  * v1 + g[6]  * v2 + g[7]  * v3;
    x[o + H]     = g[8]  * v0 + g[9]  * v1 + g[10] * v2 + g[11] * v3;
    x[o + H + L] = g[12] * v0 + g[13] * v1 + g[14] * v2 + g[15] * v3;
  }
}

// V column transform: 4-bit nibble, x bit3 = row 0; bonds (3,2),(2,1),(1,0)
template <int ST>
__device__ __forceinline__ void vxf(float* s, const float* __restrict__ g, int b) {
  float x[16];
#pragma unroll
  for (int m = 0; m < 16; ++m) x[m] = s[PAD(b + m * ST)];
  gate2<4, 3, 2>(x, g);
  gate2<4, 2, 1>(x, g);
  gate2<4, 1, 0>(x, g);
#pragma unroll
  for (int m = 0; m < 16; ++m) s[PAD(b + m * ST)] = x[m];
}

// Bond-pair round (512 threads, 1 group each): gate on (B2,B1) then (B1,B0).
template <int B2, int B1, int B0>
__device__ __forceinline__ void bondpair(float* s, const float* __restrict__ g,
                                         int t) {
  constexpr int MASK = (1 << B2) | (1 << B1) | (1 << B0);
  int b = 0, rem = t;
#pragma unroll
  for (int p = 0; p < 12; ++p) {
    if (!((MASK >> p) & 1)) {
      b |= (rem & 1) << p;
      rem >>= 1;
    }
  }
  float x[8];
#pragma unroll
  for (int m = 0; m < 8; ++m) {
    int off = ((m >> 2) & 1) * (1 << B2) + ((m >> 1) & 1) * (1 << B1) +
              (m & 1) * (1 << B0);
    x[m] = s[PAD(b + off)];
  }
  gate2<3, 2, 1>(x, g);  // bond (B2, B1)
  gate2<3, 1, 0>(x, g);  // bond (B1, B0)
#pragma unroll
  for (int m = 0; m < 8; ++m) {
    int off = ((m >> 2) & 1) * (1 << B2) + ((m >> 1) & 1) * (1 << B1) +
              (m & 1) * (1 << B0);
    s[PAD(b + off)] = x[m];
  }
}

// ---------------------------------------------------------------------------
// The fused cooperative kernel. Grid 256 x 512. Max smem use: 8224 floats.
// ---------------------------------------------------------------------------
__global__ __launch_bounds__(512, 2) void k_fused(const float* __restrict__ peps,
                                                  const int* __restrict__ x,
                                                  const float* __restrict__ gate,
                                                  float* __restrict__ ws,
                                                  float* __restrict__ out) {
  cg::grid_group gg = cg::this_grid();
  __shared__ float sm[8224];
  const int t = threadIdx.x;   // 0..511
  const int b = blockIdx.x;    // 0..255
  const int r3 = t & 255, half = t >> 8;
  float* psi = ws + PSIO;

  // ===================== phase 1: column tensors ===========================
  // cols 1..3: 192 blocks (64/col), each stages p01/p23 once, emits 2 parts.
  // cols 0,4: blocks 192,193.
  if (b < 192) {
    float* p01 = sm;           // [4096]
    float* p23 = sm + 4096;    // [4096]
    int col = 1 + (b >> 6);
    int pb = b & 63;           // -> parts 2*pb, 2*pb+1
#pragma unroll
    for (int k = 0; k < 8; ++k) {
      int e = k * 512 + t;
      int r12 = e & 15, l12 = (e >> 4) & 15, d2 = (e >> 8) & 3, p = e >> 10;
      int l1 = l12 >> 2, l2 = l12 & 3, r1 = r12 >> 2, r2 = r12 & 3;
      float s01 = 0.f, s23 = 0.f;
#pragma unroll
      for (int d = 0; d < 4; ++d) {
        s01 += peps[PIDX(0, col, (p >> 1), 0, d, l1, r1)] *
               peps[PIDX(1, col, (p & 1), d, d2, l2, r2)];
        s23 += peps[PIDX(2, col, (p >> 1), d2, d, l1, r1)] *
               peps[PIDX(3, col, (p & 1), d, 0, l2, r2)];
      }
      p01[e] = s01;
      p23[e] = s23;
    }
    __syncthreads();
    const int coloffs[3] = {COL1, COL2, COL3};
    float* outc = ws + coloffs[col - 1];
#pragma unroll
    for (int pp = 0; pp < 2; ++pp) {
      int part = pb * 2 + pp;
#pragma unroll
      for (int k = 0; k < 4; ++k) {
        int eq = part * 8192 + (k * 512 + t) * 4;
        int r34b = eq & 15;
        int r12 = (eq >> 4) & 15, l34 = (eq >> 8) & 15, l12 = (eq >> 12) & 15;
        int p = eq >> 16;
        int pa = p >> 2, pbv = p & 3;
        float4 acc = {0.f, 0.f, 0.f, 0.f};
#pragma unroll
        for (int d2 = 0; d2 < 4; ++d2) {
          float a01 = p01[((((pa * 4 + d2) << 4) | l12) << 4) | r12];
          const float4 b4 =
              *(const float4*)&p23[((((pbv * 4 + d2) << 4) | l34) << 4) | r34b];
          acc.x += a01 * b4.x;
          acc.y += a01 * b4.y;
          acc.z += a01 * b4.z;
          acc.w += a01 * b4.w;
        }
        *(float4*)&outc[eq] = acc;
      }
    }
  } else if (b < 194) {
    float* p01 = sm;
    float* p23 = sm + 4096;
    int col = (b == 192) ? 0 : 4;
    const int lsh = (col == 0) ? 0 : 2;
    const int rsh = (col == 4) ? 0 : 2;
    const int ldim = 1 << lsh, rdim = 1 << rsh;
    const int LLB = 2 * lsh, RRB = 2 * rsh;
    const int LL = 1 << LLB, RR = 1 << RRB;
    int n12 = (LL * RR) << 4;
    for (int e = t; e < n12; e += 512) {
      int r12 = e & (RR - 1);
      int l12 = (e >> RRB) & (LL - 1);
      int d2 = (e >> (RRB + LLB)) & 3;
      int p = e >> (RRB + LLB + 2);
      int l1 = l12 >> lsh, l2 = l12 & (ldim - 1);
      int r1 = r12 >> rsh, r2 = r12 & (rdim - 1);
      float s01 = 0.f, s23 = 0.f;
      for (int d = 0; d < 4; ++d) {
        s01 += peps[PIDX(0, col, (p >> 1), 0, d, l1, r1)] *
               peps[PIDX(1, col, (p & 1), d, d2, l2, r2)];
        s23 += peps[PIDX(2, col, (p >> 1), d2, d, l1, r1)] *
               peps[PIDX(3, col, (p & 1), d, 0, l2, r2)];
      }
      p01[e] = s01;
      p23[e] = s23;
    }
    __syncthreads();
    const int LB = 2 * LLB, RB = 2 * RRB;
    int total = 16 << (LB + RB);
    float* outc = ws + ((col == 0) ? COL0 : COL4);
    for (int e = t; e < total; e += 512) {
      int r = e & ((1 << RB) - 1);
      int l = (e >> RB) & ((1 << LB) - 1);
      int p = e >> (RB + LB);
      int r34 = r & (RR - 1), r12 = r >> RRB;
      int l34 = l & (LL - 1), l12 = l >> LLB;
      int pa = p >> 2, pbv = p & 3;
      float sacc = 0.f;
      for (int d2 = 0; d2 < 4; ++d2) {
        sacc += p01[((((pa * 4 + d2) << LLB) | l12) << RRB) | r12] *
                p23[((((pbv * 4 + d2) << LLB) | l34) << RRB) | r34];
      }
      outc[e] = sacc;
    }
  }
  gg.sync();

  // ===================== phase 2: M01 / M34T ===============================
  // threads 0-255: M34T for L3 = b (smem).  threads 256-511, b<64: M01 branch.
  {
    float* c3buf = sm;           // [4112]
    float* c4buf = sm + 4112;    // [4112]
    const float* col3 = ws + COL3;
    const float* col4 = ws + COL4;
    const int L3 = b;
    if (t < 256) {
      for (int e = t; e < 4096; e += 256) {
        c4buf[(e >> 8) * 257 + (e & 255)] = col4[e];
        c3buf[(e >> 8) * 257 + (e & 255)] =
            col3[(e >> 8) * 65536 + L3 * 256 + (e & 255)];
      }
    } else if (b < 64) {
      int tt = t - 256;
      int c1 = b >> 2, q = b & 3;
      int r2l = tt & 63, c0g = tt >> 6;  // wave-uniform c0 group
      int R2 = q * 64 + r2l;
      const float* col0 = ws + COL0;
      const float* col1 = ws + COL1;
      float a0 = 0.f, a1 = 0.f, a2 = 0.f, a3 = 0.f;
      for (int R1 = 0; R1 < 256; ++R1) {
        float bv = col1[(c1 * 256 + R1) * 256 + R2];  // coalesced
        a0 += col0[(c0g * 4 + 0) * 256 + R1] * bv;    // uniform -> s_load
        a1 += col0[(c0g * 4 + 1) * 256 + R1] * bv;
        a2 += col0[(c0g * 4 + 2) * 256 + R1] * bv;
        a3 += col0[(c0g * 4 + 3) * 256 + R1] * bv;
      }
      float* m01 = ws + M01TO;
      m01[((c0g * 4 + 0) * 16 + c1) * 256 + R2] = a0;  // coalesced
      m01[((c0g * 4 + 1) * 16 + c1) * 256 + R2] = a1;
      m01[((c0g * 4 + 2) * 16 + c1) * 256 + R2] = a2;
      m01[((c0g * 4 + 3) * 16 + c1) * 256 + R2] = a3;
    }
    __syncthreads();
    if (t < 256) {
      int c3 = t >> 4, c4 = t & 15;
      float acc = 0.f;
      for (int B = 0; B < 256; ++B)
        acc += c3buf[c3 * 257 + B] * c4buf[c4 * 257 + B];
      float* m34t = ws + M34TO;
      m34t[L3 * 256 + t] = acc;
    }
  }
  gg.sync();

  // ===================== phase 3: T012 = M01 x Col2 ========================
  {
    float* A = sm;  // [4096] = [i=16][R2=256]
    const float* m01 = ws + M01TO;
    const float* col2 = ws + COL2;
    float* t012p = ws + T12TO;
    int c2 = b & 15, tg = b >> 4;
#pragma unroll
    for (int k = 0; k < 2; ++k)
      *(float4*)&A[(k * 512 + t) * 4] =
          *(const float4*)&m01[tg * 4096 + (k * 512 + t) * 4];
    __syncthreads();
    float acc[8] = {};
    for (int R2 = 0; R2 < 256; R2 += 4) {
      float b0 = col2[c2 * 65536 + (R2 + 0) * 256 + r3];
      float b1 = col2[c2 * 65536 + (R2 + 1) * 256 + r3];
      float b2 = col2[c2 * 65536 + (R2 + 2) * 256 + r3];
      float b3 = col2[c2 * 65536 + (R2 + 3) * 256 + r3];
#pragma unroll
      for (int i = 0; i < 8; ++i) {
        float4 a4 = *(const float4*)&A[(half * 8 + i) * 256 + R2];
        acc[i] += a4.x * b0 + a4.y * b1 + a4.z * b2 + a4.w * b3;
      }
    }
#pragma unroll
    for (int i = 0; i < 8; ++i)
      t012p[c2 * 65536 + (tg * 16 + half * 8 + i) * 256 + r3] = acc[i];
  }
  gg.sync();

  // ===================== phase 4: psi = T012 x M34T (gate layout) ==========
  {
    float* A = sm;            // [4096] = [i=c2=16][L3=256]
    float* S = sm + 4096;     // [4112] = [c2=16][c34=257-padded]
    const float* t012p = ws + T12TO;
    const float* m34t = ws + M34TO;
    int tg = b;
#pragma unroll
    for (int i = 0; i < 8; ++i)
      A[(half * 8 + i) * 256 + r3] =
          t012p[(half * 8 + i) * 65536 + tg * 256 + r3];
    __syncthreads();
    float acc[8] = {};
    for (int L3 = 0; L3 < 256; L3 += 4) {
      float b0 = m34t[(L3 + 0) * 256 + r3];
      float b1 = m34t[(L3 + 1) * 256 + r3];
      float b2 = m34t[(L3 + 2) * 256 + r3];
      float b3 = m34t[(L3 + 3) * 256 + r3];
#pragma unroll
      for (int i = 0; i < 8; ++i) {
        float4 a4 = *(const float4*)&A[(half * 8 + i) * 256 + L3];
        acc[i] += a4.x * b0 + a4.y * b1 + a4.z * b2 + a4.w * b3;
      }
    }
#pragma unroll
    for (int i = 0; i < 8; ++i) S[(half * 8 + i) * 257 + r3] = acc[i];
    __syncthreads();
    // store: u = c3*16 + c2, v = c4 -> 64B runs (c2 lane-consecutive)
    int c3 = r3 >> 4, c2 = r3 & 15;
    int base = c3 * 65536 + (tg >> 4) * 256 + (tg & 15) * 16 + c2;
#pragma unroll
    for (int vv = 0; vv < 8; ++vv) {
      int v = half * 8 + vv;
      psi[base + v * 4096] = S[c2 * 257 + c3 * 16 + v];
    }
  }
  gg.sync();

  // ===================== phase 5: 5 x (P1, P2) gate sweeps =================
  float g[16];
#pragma unroll
  for (int i = 0; i < 16; ++i) g[i] = gate[i];
  float* s = sm;  // [5120] padded

  for (int it = 0; it < 5; ++it) {
    // ---- P1: G2_01, G2_12, M16_0, M16_1. slab = low 12 bits, o = b -------
#pragma unroll
    for (int i = 0; i < 2; ++i) {
      int f = (i * 512 + t) * 4;
      *(float4*)(s + PAD(f)) = *(const float4*)(psi + b * 4096 + f);
    }
    __syncthreads();
    bondpair<8, 4, 0>(s, g, t);
    __syncthreads();
    bondpair<9, 5, 1>(s, g, t);
    __syncthreads();
    bondpair<10, 6, 2>(s, g, t);
    __syncthreads();
    bondpair<11, 7, 3>(s, g, t);
    __syncthreads();
    if (t < 256) vxf<256>(s, g, t);                          // M16_0
    __syncthreads();
    if (t < 256) vxf<16>(s, g, ((t >> 4) << 8) | (t & 15));  // M16_1
    __syncthreads();
#pragma unroll
    for (int i = 0; i < 2; ++i) {
      int f = (i * 512 + t) * 4;
      *(float4*)(psi + b * 4096 + f) = *(const float4*)(s + PAD(f));
    }
    gg.sync();

    // ---- P2: G2_23, G2_34, M16_2..4. slab = bits {19..12,3..0}, o = b ----
#pragma unroll
    for (int i = 0; i < 2; ++i) {
      int f = (i * 512 + t) * 4;
      int addr = (f >> 8) * 65536 + ((f >> 4) & 15) * 4096 + b * 16 + (f & 15);
      *(float4*)(s + PAD(f)) = *(const float4*)(psi + addr);
    }
    __syncthreads();
    bondpair<0, 8, 4>(s, g, t);
    __syncthreads();
    bondpair<1, 9, 5>(s, g, t);
    __syncthreads();
    bondpair<2, 10, 6>(s, g, t);
    __syncthreads();
    bondpair<3, 11, 7>(s, g, t);
    __syncthreads();
    if (t < 256) vxf<1>(s, g, t * 16);                       // M16_2
    __syncthreads();
    if (t < 256) vxf<256>(s, g, t);                          // M16_3
    __syncthreads();
    if (t < 256) vxf<16>(s, g, ((t >> 4) << 8) | (t & 15));  // M16_4
    __syncthreads();
    if (it == 4) {
      if (t < 64) {
        int idx = 0;
#pragma unroll
        for (int q = 0; q < 20; ++q) {
          int i = q / 5, j = q % 5;
          int pos = (j == 0) ? (11 - i)
                   : (j == 1) ? (7 - i)
                   : (j == 2) ? (3 - i)
                   : (j == 3) ? (19 - i)
                              : (15 - i);
          idx |= x[t * 20 + q] << pos;
        }
        if (((idx >> 4) & 255) == b) {
          int local = ((idx >> 16) & 15) * 256 + ((idx >> 12) & 15) * 16 +
                      (idx & 15);
          out[t] = s[PAD(local)];
        }
      }
    } else {
#pragma unroll
      for (int i = 0; i < 2; ++i) {
        int f = (i * 512 + t) * 4;
        int addr = (f >> 8) * 65536 + ((f >> 4) & 15) * 4096 + b * 16 + (f & 15);
        *(float4*)(psi + addr) = *(const float4*)(s + PAD(f));
      }
      gg.sync();
    }
  }
}

// ---------------------------------------------------------------------------
extern "C" void kernel_launch(void* const* d_in, const int* in_sizes, int n_in,
                              void* d_out, int out_size, void* d_ws, size_t ws_size,
                              hipStream_t stream) {
  const int* x = (const int*)d_in[0];
  const float* peps = (const float*)d_in[1];
  const float* gate = (const float*)d_in[2];
  float* ws = (float*)d_ws;
  float* out = (float*)d_out;

  void* args[] = {(void*)&peps, (void*)&x, (void*)&gate, (void*)&ws, (void*)&out};
  hipLaunchCooperativeKernel((void*)k_fused, dim3(256), dim3(512), args, 0,
                             stream);
}

// Round 2
// 447.223 us; speedup vs baseline: 1.3203x; 1.3203x over previous
//
#include <hip/hip_runtime.h>

// ---------------------------------------------------------------------------
// PEPS 4x5, D=4, P=2, depth-5 gate sweeps, 64-point gather.
// Setup: 4 kernels (identical to 214us baseline).
// Gate loop: ONE persistent cooperative kernel, 9 hand-rolled grid barriers
// (monotonic-counter: threadfence -> atomicAdd(agent) -> relaxed agent spin).
// Counter zeroed by k_build_cols block 0 (prior dispatch => visible).
// Gate layout: psi idx = c3<<16 | c4<<12 | c0<<8 | c1<<4 | c2.
// ---------------------------------------------------------------------------

#define PAD(i) ((i) + (((i) >> 4) << 2))   // +4 floats per 16 -> LDS bank spread
#define PIDX(i,j,p,u,d,l,r) (((((((i)*5+(j))*2+(p))*4+(u))*4+(d))*4+(l))*4+(r))

// workspace float offsets
static constexpr int COL0  = 0;                    // [16][256]
static constexpr int COL1  = 4096;                 // [16][256][256]
static constexpr int COL2  = COL1 + 1048576;
static constexpr int COL3  = COL2 + 1048576;
static constexpr int COL4  = COL3 + 1048576;       // [16][256]
static constexpr int M01TO = COL4 + 4096;          // [c01=256][R2=256]
static constexpr int M34TO = M01TO + 65536;        // [L3=256][c34=256]
static constexpr int T12TO = M34TO + 65536;        // [c2=16][c01=256][R3=256]
static constexpr int PSIO  = T12TO + 1048576;      // [2^20] gate layout
static constexpr int CNTO  = PSIO + 1048576;       // barrier counter (int)

// --------------------------- column tensors --------------------------------
__global__ __launch_bounds__(256) void k_build_cols(const float* __restrict__ peps,
                                                    float* __restrict__ ws) {
  __shared__ float p01[4096], p23[4096];
  int bid = blockIdx.x, t = threadIdx.x;
  if (bid == 0 && t == 0) ((int*)(ws + CNTO))[0] = 0;  // barrier counter init
  if (bid < 384) {
    int col = 1 + (bid >> 7);
    int part = bid & 127;
#pragma unroll
    for (int k = 0; k < 16; ++k) {
      int e = k * 256 + t;
      int r12 = e & 15, l12 = (e >> 4) & 15, d2 = (e >> 8) & 3, p = e >> 10;
      int l1 = l12 >> 2, l2 = l12 & 3, r1 = r12 >> 2, r2 = r12 & 3;
      float s01 = 0.f, s23 = 0.f;
#pragma unroll
      for (int d = 0; d < 4; ++d) {
        s01 += peps[PIDX(0, col, (p >> 1), 0, d, l1, r1)] *
               peps[PIDX(1, col, (p & 1), d, d2, l2, r2)];
        s23 += peps[PIDX(2, col, (p >> 1), d2, d, l1, r1)] *
               peps[PIDX(3, col, (p & 1), d, 0, l2, r2)];
      }
      p01[e] = s01;
      p23[e] = s23;
    }
    __syncthreads();
    const int coloffs[3] = {COL1, COL2, COL3};
    float* out = ws + coloffs[col - 1];
#pragma unroll
    for (int k = 0; k < 8; ++k) {
      int eq = part * 8192 + (k * 256 + t) * 4;
      int r34b = eq & 15;
      int r12 = (eq >> 4) & 15, l34 = (eq >> 8) & 15, l12 = (eq >> 12) & 15;
      int p = eq >> 16;
      int pa = p >> 2, pb = p & 3;
      float4 acc = {0.f, 0.f, 0.f, 0.f};
#pragma unroll
      for (int d2 = 0; d2 < 4; ++d2) {
        float a01 = p01[((((pa * 4 + d2) << 4) | l12) << 4) | r12];
        const float4 b4 =
            *(const float4*)&p23[((((pb * 4 + d2) << 4) | l34) << 4) | r34b];
        acc.x += a01 * b4.x;
        acc.y += a01 * b4.y;
        acc.z += a01 * b4.z;
        acc.w += a01 * b4.w;
      }
      *(float4*)&out[eq] = acc;
    }
  } else {
    int col = (bid == 384) ? 0 : 4;
    const int lsh = (col == 0) ? 0 : 2;
    const int rsh = (col == 4) ? 0 : 2;
    const int ldim = 1 << lsh, rdim = 1 << rsh;
    const int LLB = 2 * lsh, RRB = 2 * rsh;
    const int LL = 1 << LLB, RR = 1 << RRB;
    int n12 = (LL * RR) << 4;
    for (int e = t; e < n12; e += 256) {
      int r12 = e & (RR - 1);
      int l12 = (e >> RRB) & (LL - 1);
      int d2 = (e >> (RRB + LLB)) & 3;
      int p = e >> (RRB + LLB + 2);
      int l1 = l12 >> lsh, l2 = l12 & (ldim - 1);
      int r1 = r12 >> rsh, r2 = r12 & (rdim - 1);
      float s01 = 0.f, s23 = 0.f;
      for (int d = 0; d < 4; ++d) {
        s01 += peps[PIDX(0, col, (p >> 1), 0, d, l1, r1)] *
               peps[PIDX(1, col, (p & 1), d, d2, l2, r2)];
        s23 += peps[PIDX(2, col, (p >> 1), d2, d, l1, r1)] *
               peps[PIDX(3, col, (p & 1), d, 0, l2, r2)];
      }
      p01[e] = s01;
      p23[e] = s23;
    }
    __syncthreads();
    const int LB = 2 * LLB, RB = 2 * RRB;
    int total = 16 << (LB + RB);  // 4096
    float* out = ws + ((col == 0) ? COL0 : COL4);
    for (int e = t; e < total; e += 256) {
      int r = e & ((1 << RB) - 1);
      int l = (e >> RB) & ((1 << LB) - 1);
      int p = e >> (RB + LB);
      int r34 = r & (RR - 1), r12 = r >> RRB;
      int l34 = l & (LL - 1), l12 = l >> LLB;
      int pa = p >> 2, pb = p & 3;
      float s = 0.f;
      for (int d2 = 0; d2 < 4; ++d2) {
        s += p01[((((pa * 4 + d2) << LLB) | l12) << RRB) | r12] *
             p23[((((pb * 4 + d2) << LLB) | l34) << RRB) | r34];
      }
      out[e] = s;
    }
  }
}

// ------------------- M01 / M34T (edge-pair contractions) -------------------
__global__ __launch_bounds__(256) void k_small(const float* __restrict__ ws,
                                               float* __restrict__ m01,
                                               float* __restrict__ m34t) {
  __shared__ float c3buf[4112], c4buf[4112];
  int t = threadIdx.x;
  if (blockIdx.x < 64) {
    int c1 = blockIdx.x >> 2, q = blockIdx.x & 3;
    int r2l = t & 63, c0g = t >> 6;  // wave-uniform c0 group (4 c0 each)
    int R2 = q * 64 + r2l;
    const float* col0 = ws + COL0;
    const float* col1 = ws + COL1;
    float a0 = 0.f, a1 = 0.f, a2 = 0.f, a3 = 0.f;
    for (int R1 = 0; R1 < 256; ++R1) {
      float bv = col1[(c1 * 256 + R1) * 256 + R2];  // coalesced
      a0 += col0[(c0g * 4 + 0) * 256 + R1] * bv;    // uniform -> s_load
      a1 += col0[(c0g * 4 + 1) * 256 + R1] * bv;
      a2 += col0[(c0g * 4 + 2) * 256 + R1] * bv;
      a3 += col0[(c0g * 4 + 3) * 256 + R1] * bv;
    }
    m01[((c0g * 4 + 0) * 16 + c1) * 256 + R2] = a0;  // coalesced
    m01[((c0g * 4 + 1) * 16 + c1) * 256 + R2] = a1;
    m01[((c0g * 4 + 2) * 16 + c1) * 256 + R2] = a2;
    m01[((c0g * 4 + 3) * 16 + c1) * 256 + R2] = a3;
  } else {
    int L3 = blockIdx.x - 64;  // 0..255
    const float* col3 = ws + COL3;
    const float* col4 = ws + COL4;
    for (int e = t; e < 4096; e += 256) {
      c4buf[(e >> 8) * 257 + (e & 255)] = col4[e];
      c3buf[(e >> 8) * 257 + (e & 255)] =
          col3[(e >> 8) * 65536 + L3 * 256 + (e & 255)];
    }
    __syncthreads();
    int c3 = t >> 4, c4 = t & 15;
    float acc = 0.f;
    for (int B = 0; B < 256; ++B)
      acc += c3buf[c3 * 257 + B] * c4buf[c4 * 257 + B];
    m34t[L3 * 256 + t] = acc;
  }
}

// ---------------- T012[c2][c01][R3] = M01 x Col2 ---------------------------
__global__ __launch_bounds__(256) void k_t012(const float* __restrict__ m01,
                                              const float* __restrict__ col2,
                                              float* __restrict__ t012) {
  __shared__ float A[4096];  // [i=16][R2=256]
  int t = threadIdx.x;       // R3
  int c2 = blockIdx.x & 15, tg = blockIdx.x >> 4;
#pragma unroll
  for (int k = 0; k < 4; ++k)
    *(float4*)&A[(k * 256 + t) * 4] =
        *(const float4*)&m01[tg * 4096 + (k * 256 + t) * 4];
  __syncthreads();
  float acc[16] = {};
  for (int R2 = 0; R2 < 256; R2 += 4) {
    float b0 = col2[c2 * 65536 + (R2 + 0) * 256 + t];
    float b1 = col2[c2 * 65536 + (R2 + 1) * 256 + t];
    float b2 = col2[c2 * 65536 + (R2 + 2) * 256 + t];
    float b3 = col2[c2 * 65536 + (R2 + 3) * 256 + t];
#pragma unroll
    for (int i = 0; i < 16; ++i) {
      float4 a4 = *(const float4*)&A[i * 256 + R2];  // broadcast b128
      acc[i] += a4.x * b0 + a4.y * b1 + a4.z * b2 + a4.w * b3;
    }
  }
#pragma unroll
  for (int i = 0; i < 16; ++i)
    t012[c2 * 65536 + (tg * 16 + i) * 256 + t] = acc[i];  // coalesced
}

// ---------------- psi = T012 x M34T, emitted in GATE layout ----------------
__global__ __launch_bounds__(256) void k_psi0(const float* __restrict__ t012,
                                              const float* __restrict__ m34t,
                                              float* __restrict__ psi) {
  __shared__ float A[4096];  // [i=c2=16][L3=256]
  __shared__ float S[4112];  // [c2=16][c34=257-padded]
  int t = threadIdx.x;       // c34 (and L3 for staging)
  int tg = blockIdx.x;       // c01
#pragma unroll
  for (int i = 0; i < 16; ++i)
    A[i * 256 + t] = t012[i * 65536 + tg * 256 + t];  // coalesced 1KB chunks
  __syncthreads();
  float acc[16] = {};
  for (int L3 = 0; L3 < 256; L3 += 4) {
    float b0 = m34t[(L3 + 0) * 256 + t];
    float b1 = m34t[(L3 + 1) * 256 + t];
    float b2 = m34t[(L3 + 2) * 256 + t];
    float b3 = m34t[(L3 + 3) * 256 + t];
#pragma unroll
    for (int i = 0; i < 16; ++i) {
      float4 a4 = *(const float4*)&A[i * 256 + L3];  // broadcast b128
      acc[i] += a4.x * b0 + a4.y * b1 + a4.z * b2 + a4.w * b3;
    }
  }
#pragma unroll
  for (int i = 0; i < 16; ++i) S[i * 257 + t] = acc[i];
  __syncthreads();
  // store: u = c3*16 + c2, v = c4 -> 64B runs (c2 lane-consecutive)
  int c3 = t >> 4, c2 = t & 15;
  int base = c3 * 65536 + (tg >> 4) * 256 + (tg & 15) * 16 + c2;
#pragma unroll
  for (int v = 0; v < 16; ++v)
    psi[base + v * 4096] = S[c2 * 257 + c3 * 16 + v];
}

// ---------------- register-level 2-qubit gate ------------------------------
template <int NB, int HI, int LO>
__device__ __forceinline__ void gate2(float* x, const float* __restrict__ g) {
  constexpr int H = 1 << HI, L = 1 << LO, N = 1 << NB;
#pragma unroll
  for (int o = 0; o < N; ++o) {
    if (o & (H | L)) continue;
    float v0 = x[o], v1 = x[o + L], v2 = x[o + H], v3 = x[o + H + L];
    x[o]         = g[0]  * v0 + g[1]  * v1 + g[2]  * v2 + g[3]  * v3;
    x[o + L]     = g[4]  * v0 + g[5]  * v1 + g[6]  * v2 + g[7]  * v3;
    x[o + H]     = g[8]  * v0 + g[9]  * v1 + g[10] * v2 + g[11] * v3;
    x[o + H + L] = g[12] * v0 + g[13] * v1 + g[14] * v2 + g[15] * v3;
  }
}

// V column transform: 4-bit nibble, x bit3 = row 0; bonds (3,2),(2,1),(1,0)
template <int ST>
__device__ __forceinline__ void vxf(float* s, const float* __restrict__ g, int b) {
  float x[16];
#pragma unroll
  for (int m = 0; m < 16; ++m) x[m] = s[PAD(b + m * ST)];
  gate2<4, 3, 2>(x, g);
  gate2<4, 2, 1>(x, g);
  gate2<4, 1, 0>(x, g);
#pragma unroll
  for (int m = 0; m < 16; ++m) s[PAD(b + m * ST)] = x[m];
}

// Bond-pair round (512 threads, 1 group each): gate on (B2,B1) then (B1,B0).
template <int B2, int B1, int B0>
__device__ __forceinline__ void bondpair(float* s, const float* __restrict__ g,
                                         int t) {
  constexpr int MASK = (1 << B2) | (1 << B1) | (1 << B0);
  int b = 0, rem = t;
#pragma unroll
  for (int p = 0; p < 12; ++p) {
    if (!((MASK >> p) & 1)) {
      b |= (rem & 1) << p;
      rem >>= 1;
    }
  }
  float x[8];
#pragma unroll
  for (int m = 0; m < 8; ++m) {
    int off = ((m >> 2) & 1) * (1 << B2) + ((m >> 1) & 1) * (1 << B1) +
              (m & 1) * (1 << B0);
    x[m] = s[PAD(b + off)];
  }
  gate2<3, 2, 1>(x, g);  // bond (B2, B1)
  gate2<3, 1, 0>(x, g);  // bond (B1, B0)
#pragma unroll
  for (int m = 0; m < 8; ++m) {
    int off = ((m >> 2) & 1) * (1 << B2) + ((m >> 1) & 1) * (1 << B1) +
              (m & 1) * (1 << B0);
    s[PAD(b + off)] = x[m];
  }
}

// ---------------- hand-rolled grid barrier ---------------------------------
// Monotonic counter; zeroed by k_build_cols (earlier dispatch).
// release fence -> arrive -> relaxed agent-scope spin -> acquire fence.
__device__ __forceinline__ void gridbar(int* __restrict__ cnt, int tgt) {
  __syncthreads();                 // all block stores drained (vmcnt 0)
  if (threadIdx.x == 0) {
    __threadfence();               // agent release: L2 writeback
    atomicAdd(cnt, 1);             // device-scope arrive
    while (__hip_atomic_load(cnt, __ATOMIC_RELAXED,
                             __HIP_MEMORY_SCOPE_AGENT) < tgt) {
      __builtin_amdgcn_s_sleep(1);
    }
    __threadfence();               // agent acquire: invalidate stale lines
  }
  __syncthreads();
}

// ---------------- persistent gate loop: 5 x (P1, P2), 9 barriers -----------
__global__ __launch_bounds__(512) void k_gates(float* __restrict__ psi,
                                               const float* __restrict__ gate,
                                               const int* __restrict__ x,
                                               float* __restrict__ out,
                                               int* __restrict__ cnt) {
  __shared__ float s[5120];
  float g[16];
#pragma unroll
  for (int i = 0; i < 16; ++i) g[i] = gate[i];
  const int t = threadIdx.x;  // 512
  const int b = blockIdx.x;   // 256
  int barid = 0;

  for (int it = 0; it < 5; ++it) {
    // ---- P1: G2_01, G2_12, M16_0, M16_1. slab = low 12 bits, o = b -------
#pragma unroll
    for (int i = 0; i < 2; ++i) {
      int f = (i * 512 + t) * 4;
      *(float4*)(s + PAD(f)) = *(const float4*)(psi + b * 4096 + f);
    }
    __syncthreads();
    bondpair<8, 4, 0>(s, g, t);
    __syncthreads();
    bondpair<9, 5, 1>(s, g, t);
    __syncthreads();
    bondpair<10, 6, 2>(s, g, t);
    __syncthreads();
    bondpair<11, 7, 3>(s, g, t);
    __syncthreads();
    if (t < 256) vxf<256>(s, g, t);                          // M16_0
    __syncthreads();
    if (t < 256) vxf<16>(s, g, ((t >> 4) << 8) | (t & 15));  // M16_1
    __syncthreads();
#pragma unroll
    for (int i = 0; i < 2; ++i) {
      int f = (i * 512 + t) * 4;
      *(float4*)(psi + b * 4096 + f) = *(const float4*)(s + PAD(f));
    }
    ++barid;
    gridbar(cnt, barid * 256);

    // ---- P2: G2_23, G2_34, M16_2..4. slab = bits {19..12,3..0}, o = b ----
#pragma unroll
    for (int i = 0; i < 2; ++i) {
      int f = (i * 512 + t) * 4;
      int addr = (f >> 8) * 65536 + ((f >> 4) & 15) * 4096 + b * 16 + (f & 15);
      *(float4*)(s + PAD(f)) = *(const float4*)(psi + addr);
    }
    __syncthreads();
    bondpair<0, 8, 4>(s, g, t);
    __syncthreads();
    bondpair<1, 9, 5>(s, g, t);
    __syncthreads();
    bondpair<2, 10, 6>(s, g, t);
    __syncthreads();
    bondpair<3, 11, 7>(s, g, t);
    __syncthreads();
    if (t < 256) vxf<1>(s, g, t * 16);                       // M16_2
    __syncthreads();
    if (t < 256) vxf<256>(s, g, t);                          // M16_3
    __syncthreads();
    if (t < 256) vxf<16>(s, g, ((t >> 4) << 8) | (t & 15));  // M16_4
    __syncthreads();
    if (it == 4) {
      if (t < 64) {
        int idx = 0;
#pragma unroll
        for (int q = 0; q < 20; ++q) {
          int i = q / 5, j = q % 5;
          int pos = (j == 0) ? (11 - i)
                   : (j == 1) ? (7 - i)
                   : (j == 2) ? (3 - i)
                   : (j == 3) ? (19 - i)
                              : (15 - i);
          idx |= x[t * 20 + q] << pos;
        }
        if (((idx >> 4) & 255) == b) {
          int local = ((idx >> 16) & 15) * 256 + ((idx >> 12) & 15) * 16 +
                      (idx & 15);
          out[t] = s[PAD(local)];
        }
      }
    } else {
#pragma unroll
      for (int i = 0; i < 2; ++i) {
        int f = (i * 512 + t) * 4;
        int addr = (f >> 8) * 65536 + ((f >> 4) & 15) * 4096 + b * 16 + (f & 15);
        *(float4*)(psi + addr) = *(const float4*)(s + PAD(f));
      }
      ++barid;
      gridbar(cnt, barid * 256);
    }
  }
}

// ---------------------------------------------------------------------------
extern "C" void kernel_launch(void* const* d_in, const int* in_sizes, int n_in,
                              void* d_out, int out_size, void* d_ws, size_t ws_size,
                              hipStream_t stream) {
  const int* x = (const int*)d_in[0];
  const float* peps = (const float*)d_in[1];
  const float* gate = (const float*)d_in[2];
  float* ws = (float*)d_ws;
  float* psi = ws + PSIO;
  float* out = (float*)d_out;
  int* cnt = (int*)(ws + CNTO);

  k_build_cols<<<386, 256, 0, stream>>>(peps, ws);
  k_small<<<320, 256, 0, stream>>>(ws, ws + M01TO, ws + M34TO);
  k_t012<<<256, 256, 0, stream>>>(ws + M01TO, ws + COL2, ws + T12TO);
  k_psi0<<<256, 256, 0, stream>>>(ws + T12TO, ws + M34TO, psi);

  void* args[] = {(void*)&psi, (void*)&gate, (void*)&x, (void*)&out,
                  (void*)&cnt};
  hipLaunchCooperativeKernel((void*)k_gates, dim3(256), dim3(512), args, 0,
                             stream);
}

// Round 3
// 268.584 us; speedup vs baseline: 2.1984x; 1.6651x over previous
//
#include <hip/hip_runtime.h>

// ---------------------------------------------------------------------------
// PEPS 4x5, D=4, P=2, depth-5 gate sweeps, 64-point gather.
// Setup: 4 kernels (identical to 214us baseline).
// Gate loop: ONE persistent cooperative kernel.
//   - psi accessed ONLY via relaxed agent-scope atomics (sc0 sc1: read/write
//     through to the coherent point; L2 never holds dirty/stale psi lines).
//   - grid barrier = two-level arrival tree (16 groups x 16 + root) of
//     relaxed agent atomics. NO threadfence => NO buffer_wbl2 L2 walks.
// Gate layout: psi idx = c3<<16 | c4<<12 | c0<<8 | c1<<4 | c2.
// ---------------------------------------------------------------------------

#define PAD(i) ((i) + (((i) >> 4) << 2))   // +4 floats per 16 -> LDS bank spread
#define PIDX(i,j,p,u,d,l,r) (((((((i)*5+(j))*2+(p))*4+(u))*4+(d))*4+(l))*4+(r))

// workspace float offsets
static constexpr int COL0  = 0;                    // [16][256]
static constexpr int COL1  = 4096;                 // [16][256][256]
static constexpr int COL2  = COL1 + 1048576;
static constexpr int COL3  = COL2 + 1048576;
static constexpr int COL4  = COL3 + 1048576;       // [16][256]
static constexpr int M01TO = COL4 + 4096;          // [c01=256][R2=256]
static constexpr int M34TO = M01TO + 65536;        // [L3=256][c34=256]
static constexpr int T12TO = M34TO + 65536;        // [c2=16][c01=256][R3=256]
static constexpr int PSIO  = T12TO + 1048576;      // [2^20] gate layout
static constexpr int CNTO  = PSIO + 1048576;       // barrier tree: 17 lines x 64 ints

// --------------------------- column tensors --------------------------------
__global__ __launch_bounds__(256) void k_build_cols(const float* __restrict__ peps,
                                                    float* __restrict__ ws) {
  __shared__ float p01[4096], p23[4096];
  int bid = blockIdx.x, t = threadIdx.x;
  if (bid == 0) {  // zero barrier tree (visible to k_gates via kernel boundary)
    int* c = (int*)(ws + CNTO);
    for (int e = t; e < 1088; e += 256) c[e] = 0;
  }
  if (bid < 384) {
    int col = 1 + (bid >> 7);
    int part = bid & 127;
#pragma unroll
    for (int k = 0; k < 16; ++k) {
      int e = k * 256 + t;
      int r12 = e & 15, l12 = (e >> 4) & 15, d2 = (e >> 8) & 3, p = e >> 10;
      int l1 = l12 >> 2, l2 = l12 & 3, r1 = r12 >> 2, r2 = r12 & 3;
      float s01 = 0.f, s23 = 0.f;
#pragma unroll
      for (int d = 0; d < 4; ++d) {
        s01 += peps[PIDX(0, col, (p >> 1), 0, d, l1, r1)] *
               peps[PIDX(1, col, (p & 1), d, d2, l2, r2)];
        s23 += peps[PIDX(2, col, (p >> 1), d2, d, l1, r1)] *
               peps[PIDX(3, col, (p & 1), d, 0, l2, r2)];
      }
      p01[e] = s01;
      p23[e] = s23;
    }
    __syncthreads();
    const int coloffs[3] = {COL1, COL2, COL3};
    float* out = ws + coloffs[col - 1];
#pragma unroll
    for (int k = 0; k < 8; ++k) {
      int eq = part * 8192 + (k * 256 + t) * 4;
      int r34b = eq & 15;
      int r12 = (eq >> 4) & 15, l34 = (eq >> 8) & 15, l12 = (eq >> 12) & 15;
      int p = eq >> 16;
      int pa = p >> 2, pb = p & 3;
      float4 acc = {0.f, 0.f, 0.f, 0.f};
#pragma unroll
      for (int d2 = 0; d2 < 4; ++d2) {
        float a01 = p01[((((pa * 4 + d2) << 4) | l12) << 4) | r12];
        const float4 b4 =
            *(const float4*)&p23[((((pb * 4 + d2) << 4) | l34) << 4) | r34b];
        acc.x += a01 * b4.x;
        acc.y += a01 * b4.y;
        acc.z += a01 * b4.z;
        acc.w += a01 * b4.w;
      }
      *(float4*)&out[eq] = acc;
    }
  } else {
    int col = (bid == 384) ? 0 : 4;
    const int lsh = (col == 0) ? 0 : 2;
    const int rsh = (col == 4) ? 0 : 2;
    const int ldim = 1 << lsh, rdim = 1 << rsh;
    const int LLB = 2 * lsh, RRB = 2 * rsh;
    const int LL = 1 << LLB, RR = 1 << RRB;
    int n12 = (LL * RR) << 4;
    for (int e = t; e < n12; e += 256) {
      int r12 = e & (RR - 1);
      int l12 = (e >> RRB) & (LL - 1);
      int d2 = (e >> (RRB + LLB)) & 3;
      int p = e >> (RRB + LLB + 2);
      int l1 = l12 >> lsh, l2 = l12 & (ldim - 1);
      int r1 = r12 >> rsh, r2 = r12 & (rdim - 1);
      float s01 = 0.f, s23 = 0.f;
      for (int d = 0; d < 4; ++d) {
        s01 += peps[PIDX(0, col, (p >> 1), 0, d, l1, r1)] *
               peps[PIDX(1, col, (p & 1), d, d2, l2, r2)];
        s23 += peps[PIDX(2, col, (p >> 1), d2, d, l1, r1)] *
               peps[PIDX(3, col, (p & 1), d, 0, l2, r2)];
      }
      p01[e] = s01;
      p23[e] = s23;
    }
    __syncthreads();
    const int LB = 2 * LLB, RB = 2 * RRB;
    int total = 16 << (LB + RB);  // 4096
    float* out = ws + ((col == 0) ? COL0 : COL4);
    for (int e = t; e < total; e += 256) {
      int r = e & ((1 << RB) - 1);
      int l = (e >> RB) & ((1 << LB) - 1);
      int p = e >> (RB + LB);
      int r34 = r & (RR - 1), r12 = r >> RRB;
      int l34 = l & (LL - 1), l12 = l >> LLB;
      int pa = p >> 2, pb = p & 3;
      float s = 0.f;
      for (int d2 = 0; d2 < 4; ++d2) {
        s += p01[((((pa * 4 + d2) << LLB) | l12) << RRB) | r12] *
             p23[((((pb * 4 + d2) << LLB) | l34) << RRB) | r34];
      }
      out[e] = s;
    }
  }
}

// ------------------- M01 / M34T (edge-pair contractions) -------------------
__global__ __launch_bounds__(256) void k_small(const float* __restrict__ ws,
                                               float* __restrict__ m01,
                                               float* __restrict__ m34t) {
  __shared__ float c3buf[4112], c4buf[4112];
  int t = threadIdx.x;
  if (blockIdx.x < 64) {
    int c1 = blockIdx.x >> 2, q = blockIdx.x & 3;
    int r2l = t & 63, c0g = t >> 6;  // wave-uniform c0 group (4 c0 each)
    int R2 = q * 64 + r2l;
    const float* col0 = ws + COL0;
    const float* col1 = ws + COL1;
    float a0 = 0.f, a1 = 0.f, a2 = 0.f, a3 = 0.f;
    for (int R1 = 0; R1 < 256; ++R1) {
      float bv = col1[(c1 * 256 + R1) * 256 + R2];  // coalesced
      a0 += col0[(c0g * 4 + 0) * 256 + R1] * bv;    // uniform -> s_load
      a1 += col0[(c0g * 4 + 1) * 256 + R1] * bv;
      a2 += col0[(c0g * 4 + 2) * 256 + R1] * bv;
      a3 += col0[(c0g * 4 + 3) * 256 + R1] * bv;
    }
    m01[((c0g * 4 + 0) * 16 + c1) * 256 + R2] = a0;  // coalesced
    m01[((c0g * 4 + 1) * 16 + c1) * 256 + R2] = a1;
    m01[((c0g * 4 + 2) * 16 + c1) * 256 + R2] = a2;
    m01[((c0g * 4 + 3) * 16 + c1) * 256 + R2] = a3;
  } else {
    int L3 = blockIdx.x - 64;  // 0..255
    const float* col3 = ws + COL3;
    const float* col4 = ws + COL4;
    for (int e = t; e < 4096; e += 256) {
      c4buf[(e >> 8) * 257 + (e & 255)] = col4[e];
      c3buf[(e >> 8) * 257 + (e & 255)] =
          col3[(e >> 8) * 65536 + L3 * 256 + (e & 255)];
    }
    __syncthreads();
    int c3 = t >> 4, c4 = t & 15;
    float acc = 0.f;
    for (int B = 0; B < 256; ++B)
      acc += c3buf[c3 * 257 + B] * c4buf[c4 * 257 + B];
    m34t[L3 * 256 + t] = acc;
  }
}

// ---------------- T012[c2][c01][R3] = M01 x Col2 ---------------------------
__global__ __launch_bounds__(256) void k_t012(const float* __restrict__ m01,
                                              const float* __restrict__ col2,
                                              float* __restrict__ t012) {
  __shared__ float A[4096];  // [i=16][R2=256]
  int t = threadIdx.x;       // R3
  int c2 = blockIdx.x & 15, tg = blockIdx.x >> 4;
#pragma unroll
  for (int k = 0; k < 4; ++k)
    *(float4*)&A[(k * 256 + t) * 4] =
        *(const float4*)&m01[tg * 4096 + (k * 256 + t) * 4];
  __syncthreads();
  float acc[16] = {};
  for (int R2 = 0; R2 < 256; R2 += 4) {
    float b0 = col2[c2 * 65536 + (R2 + 0) * 256 + t];
    float b1 = col2[c2 * 65536 + (R2 + 1) * 256 + t];
    float b2 = col2[c2 * 65536 + (R2 + 2) * 256 + t];
    float b3 = col2[c2 * 65536 + (R2 + 3) * 256 + t];
#pragma unroll
    for (int i = 0; i < 16; ++i) {
      float4 a4 = *(const float4*)&A[i * 256 + R2];  // broadcast b128
      acc[i] += a4.x * b0 + a4.y * b1 + a4.z * b2 + a4.w * b3;
    }
  }
#pragma unroll
  for (int i = 0; i < 16; ++i)
    t012[c2 * 65536 + (tg * 16 + i) * 256 + t] = acc[i];  // coalesced
}

// ---------------- psi = T012 x M34T, emitted in GATE layout ----------------
__global__ __launch_bounds__(256) void k_psi0(const float* __restrict__ t012,
                                              const float* __restrict__ m34t,
                                              float* __restrict__ psi) {
  __shared__ float A[4096];  // [i=c2=16][L3=256]
  __shared__ float S[4112];  // [c2=16][c34=257-padded]
  int t = threadIdx.x;       // c34 (and L3 for staging)
  int tg = blockIdx.x;       // c01
#pragma unroll
  for (int i = 0; i < 16; ++i)
    A[i * 256 + t] = t012[i * 65536 + tg * 256 + t];  // coalesced 1KB chunks
  __syncthreads();
  float acc[16] = {};
  for (int L3 = 0; L3 < 256; L3 += 4) {
    float b0 = m34t[(L3 + 0) * 256 + t];
    float b1 = m34t[(L3 + 1) * 256 + t];
    float b2 = m34t[(L3 + 2) * 256 + t];
    float b3 = m34t[(L3 + 3) * 256 + t];
#pragma unroll
    for (int i = 0; i < 16; ++i) {
      float4 a4 = *(const float4*)&A[i * 256 + L3];  // broadcast b128
      acc[i] += a4.x * b0 + a4.y * b1 + a4.z * b2 + a4.w * b3;
    }
  }
#pragma unroll
  for (int i = 0; i < 16; ++i) S[i * 257 + t] = acc[i];
  __syncthreads();
  // store: u = c3*16 + c2, v = c4 -> 64B runs (c2 lane-consecutive)
  int c3 = t >> 4, c2 = t & 15;
  int base = c3 * 65536 + (tg >> 4) * 256 + (tg & 15) * 16 + c2;
#pragma unroll
  for (int v = 0; v < 16; ++v)
    psi[base + v * 4096] = S[c2 * 257 + c3 * 16 + v];
}

// ---------------- register-level 2-qubit gate ------------------------------
template <int NB, int HI, int LO>
__device__ __forceinline__ void gate2(float* x, const float* __restrict__ g) {
  constexpr int H = 1 << HI, L = 1 << LO, N = 1 << NB;
#pragma unroll
  for (int o = 0; o < N; ++o) {
    if (o & (H | L)) continue;
    float v0 = x[o], v1 = x[o + L], v2 = x[o + H], v3 = x[o + H + L];
    x[o]         = g[0]  * v0 + g[1]  * v1 + g[2]  * v2 + g[3]  * v3;
    x[o + L]     = g[4]  * v0 + g[5]  * v1 + g[6]  * v2 + g[7]  * v3;
    x[o + H]     = g[8]  * v0 + g[9]  * v1 + g[10] * v2 + g[11] * v3;
    x[o + H + L] = g[12] * v0 + g[13] * v1 + g[14] * v2 + g[15] * v3;
  }
}

// V column transform: 4-bit nibble, x bit3 = row 0; bonds (3,2),(2,1),(1,0)
template <int ST>
__device__ __forceinline__ void vxf(float* s, const float* __restrict__ g, int b) {
  float x[16];
#pragma unroll
  for (int m = 0; m < 16; ++m) x[m] = s[PAD(b + m * ST)];
  gate2<4, 3, 2>(x, g);
  gate2<4, 2, 1>(x, g);
  gate2<4, 1, 0>(x, g);
#pragma unroll
  for (int m = 0; m < 16; ++m) s[PAD(b + m * ST)] = x[m];
}

// Bond-pair round (512 threads, 1 group each): gate on (B2,B1) then (B1,B0).
template <int B2, int B1, int B0>
__device__ __forceinline__ void bondpair(float* s, const float* __restrict__ g,
                                         int t) {
  constexpr int MASK = (1 << B2) | (1 << B1) | (1 << B0);
  int b = 0, rem = t;
#pragma unroll
  for (int p = 0; p < 12; ++p) {
    if (!((MASK >> p) & 1)) {
      b |= (rem & 1) << p;
      rem >>= 1;
    }
  }
  float x[8];
#pragma unroll
  for (int m = 0; m < 8; ++m) {
    int off = ((m >> 2) & 1) * (1 << B2) + ((m >> 1) & 1) * (1 << B1) +
              (m & 1) * (1 << B0);
    x[m] = s[PAD(b + off)];
  }
  gate2<3, 2, 1>(x, g);  // bond (B2, B1)
  gate2<3, 1, 0>(x, g);  // bond (B1, B0)
#pragma unroll
  for (int m = 0; m < 8; ++m) {
    int off = ((m >> 2) & 1) * (1 << B2) + ((m >> 1) & 1) * (1 << B1) +
              (m & 1) * (1 << B0);
    s[PAD(b + off)] = x[m];
  }
}

// ---------------- agent-scope (coherent-point) psi access ------------------
__device__ __forceinline__ float agl(const float* p) {
  return __hip_atomic_load(p, __ATOMIC_RELAXED, __HIP_MEMORY_SCOPE_AGENT);
}
__device__ __forceinline__ void ags(float* p, float v) {
  __hip_atomic_store(p, v, __ATOMIC_RELAXED, __HIP_MEMORY_SCOPE_AGENT);
}

// ---------------- two-level fence-free grid barrier ------------------------
// Tree: 16 group counters (256B apart) + root. All relaxed agent atomics.
// Correct because ALL shared data (psi) moves via agent-scope atomics: no
// L2-dirty/stale state exists, so no wbl2/inv fences are needed; per-wave
// vmcnt(0) before s_barrier orders stores before the arrive RMW.
__device__ __forceinline__ void gridbar(int* cnts, int gen) {
  __syncthreads();  // drains vmcnt -> psi stores completed at coherent point
  if (threadIdx.x == 0) {
    int* gc = cnts + (blockIdx.x >> 4) * 64;
    int* root = cnts + 1024;
    int prev = __hip_atomic_fetch_add(gc, 1, __ATOMIC_RELAXED,
                                      __HIP_MEMORY_SCOPE_AGENT);
    if ((prev & 15) == 15)  // last of the 16 blocks in this group
      __hip_atomic_fetch_add(root, 1, __ATOMIC_RELAXED,
                             __HIP_MEMORY_SCOPE_AGENT);
    while (__hip_atomic_load(root, __ATOMIC_RELAXED,
                             __HIP_MEMORY_SCOPE_AGENT) < gen * 16) {
      __builtin_amdgcn_s_sleep(2);
    }
  }
  __syncthreads();
}

// ---------------- persistent gate loop: 5 x (P1, P2), 9 barriers -----------
__global__ __launch_bounds__(512) void k_gates(float* __restrict__ psi,
                                               const float* __restrict__ gate,
                                               const int* __restrict__ x,
                                               float* __restrict__ out,
                                               int* __restrict__ cnt) {
  __shared__ float s[5120];
  float g[16];
#pragma unroll
  for (int i = 0; i < 16; ++i) g[i] = gate[i];
  const int t = threadIdx.x;  // 512
  const int b = blockIdx.x;   // 256
  int gen = 0;

  for (int it = 0; it < 5; ++it) {
    // ---- P1: G2_01, G2_12, M16_0, M16_1. slab = low 12 bits, o = b -------
#pragma unroll
    for (int i = 0; i < 2; ++i) {
      int f = (i * 512 + t) * 4;
      const float* p = psi + b * 4096 + f;
      float4 v;
      v.x = agl(p + 0); v.y = agl(p + 1); v.z = agl(p + 2); v.w = agl(p + 3);
      *(float4*)(s + PAD(f)) = v;
    }
    __syncthreads();
    bondpair<8, 4, 0>(s, g, t);
    __syncthreads();
    bondpair<9, 5, 1>(s, g, t);
    __syncthreads();
    bondpair<10, 6, 2>(s, g, t);
    __syncthreads();
    bondpair<11, 7, 3>(s, g, t);
    __syncthreads();
    if (t < 256) vxf<256>(s, g, t);                          // M16_0
    __syncthreads();
    if (t < 256) vxf<16>(s, g, ((t >> 4) << 8) | (t & 15));  // M16_1
    __syncthreads();
#pragma unroll
    for (int i = 0; i < 2; ++i) {
      int f = (i * 512 + t) * 4;
      float4 v = *(const float4*)(s + PAD(f));
      float* p = psi + b * 4096 + f;
      ags(p + 0, v.x); ags(p + 1, v.y); ags(p + 2, v.z); ags(p + 3, v.w);
    }
    ++gen;
    gridbar(cnt, gen);

    // ---- P2: G2_23, G2_34, M16_2..4. slab = bits {19..12,3..0}, o = b ----
#pragma unroll
    for (int i = 0; i < 2; ++i) {
      int f = (i * 512 + t) * 4;
      int addr = (f >> 8) * 65536 + ((f >> 4) & 15) * 4096 + b * 16 + (f & 15);
      const float* p = psi + addr;
      float4 v;
      v.x = agl(p + 0); v.y = agl(p + 1); v.z = agl(p + 2); v.w = agl(p + 3);
      *(float4*)(s + PAD(f)) = v;
    }
    __syncthreads();
    bondpair<0, 8, 4>(s, g, t);
    __syncthreads();
    bondpair<1, 9, 5>(s, g, t);
    __syncthreads();
    bondpair<2, 10, 6>(s, g, t);
    __syncthreads();
    bondpair<3, 11, 7>(s, g, t);
    __syncthreads();
    if (t < 256) vxf<1>(s, g, t * 16);                       // M16_2
    __syncthreads();
    if (t < 256) vxf<256>(s, g, t);                          // M16_3
    __syncthreads();
    if (t < 256) vxf<16>(s, g, ((t >> 4) << 8) | (t & 15));  // M16_4
    __syncthreads();
    if (it == 4) {
      if (t < 64) {
        int idx = 0;
#pragma unroll
        for (int q = 0; q < 20; ++q) {
          int i = q / 5, j = q % 5;
          int pos = (j == 0) ? (11 - i)
                   : (j == 1) ? (7 - i)
                   : (j == 2) ? (3 - i)
                   : (j == 3) ? (19 - i)
                              : (15 - i);
          idx |= x[t * 20 + q] << pos;
        }
        if (((idx >> 4) & 255) == b) {
          int local = ((idx >> 16) & 15) * 256 + ((idx >> 12) & 15) * 16 +
                      (idx & 15);
          out[t] = s[PAD(local)];
        }
      }
    } else {
#pragma unroll
      for (int i = 0; i < 2; ++i) {
        int f = (i * 512 + t) * 4;
        int addr = (f >> 8) * 65536 + ((f >> 4) & 15) * 4096 + b * 16 + (f & 15);
        float4 v = *(const float4*)(s + PAD(f));
        float* p = psi + addr;
        ags(p + 0, v.x); ags(p + 1, v.y); ags(p + 2, v.z); ags(p + 3, v.w);
      }
      ++gen;
      gridbar(cnt, gen);
    }
  }
}

// ---------------------------------------------------------------------------
extern "C" void kernel_launch(void* const* d_in, const int* in_sizes, int n_in,
                              void* d_out, int out_size, void* d_ws, size_t ws_size,
                              hipStream_t stream) {
  const int* x = (const int*)d_in[0];
  const float* peps = (const float*)d_in[1];
  const float* gate = (const float*)d_in[2];
  float* ws = (float*)d_ws;
  float* psi = ws + PSIO;
  float* out = (float*)d_out;
  int* cnt = (int*)(ws + CNTO);

  k_build_cols<<<386, 256, 0, stream>>>(peps, ws);
  k_small<<<320, 256, 0, stream>>>(ws, ws + M01TO, ws + M34TO);
  k_t012<<<256, 256, 0, stream>>>(ws + M01TO, ws + COL2, ws + T12TO);
  k_psi0<<<256, 256, 0, stream>>>(ws + T12TO, ws + M34TO, psi);

  void* args[] = {(void*)&psi, (void*)&gate, (void*)&x, (void*)&out,
                  (void*)&cnt};
  hipLaunchCooperativeKernel((void*)k_gates, dim3(256), dim3(512), args, 0,
                             stream);
}

// Round 4
// 244.542 us; speedup vs baseline: 2.4146x; 1.0983x over previous
//
#include <hip/hip_runtime.h>

// ---------------------------------------------------------------------------
// PEPS 4x5, D=4, P=2, depth-5 gate sweeps, 64-point gather.
// Setup: 4 kernels (identical to 214us baseline).
// Gate loop: ONE persistent cooperative kernel.
//   - psi accessed ONLY via 16B coherent loads/stores (global_*_dwordx4
//     sc0 sc1: bypass L1+L2 to the coherent point; L2 never holds
//     dirty/stale psi lines; full write-combining, no 4x amplification).
//   - grid barrier = two-level arrival tree (16 groups x 16 + root) of
//     relaxed agent atomics. NO threadfence => NO buffer_wbl2 L2 walks.
//     Explicit s_waitcnt vmcnt(0) before arrive (asm stores untracked).
// Gate layout: psi idx = c3<<16 | c4<<12 | c0<<8 | c1<<4 | c2.
// ---------------------------------------------------------------------------

#define PAD(i) ((i) + (((i) >> 4) << 2))   // +4 floats per 16 -> LDS bank spread
#define PIDX(i,j,p,u,d,l,r) (((((((i)*5+(j))*2+(p))*4+(u))*4+(d))*4+(l))*4+(r))

typedef float v4f __attribute__((ext_vector_type(4)));

// workspace float offsets
static constexpr int COL0  = 0;                    // [16][256]
static constexpr int COL1  = 4096;                 // [16][256][256]
static constexpr int COL2  = COL1 + 1048576;
static constexpr int COL3  = COL2 + 1048576;
static constexpr int COL4  = COL3 + 1048576;       // [16][256]
static constexpr int M01TO = COL4 + 4096;          // [c01=256][R2=256]
static constexpr int M34TO = M01TO + 65536;        // [L3=256][c34=256]
static constexpr int T12TO = M34TO + 65536;        // [c2=16][c01=256][R3=256]
static constexpr int PSIO  = T12TO + 1048576;      // [2^20] gate layout
static constexpr int CNTO  = PSIO + 1048576;       // barrier tree: 17 lines x 64 ints

// --------------------------- column tensors --------------------------------
__global__ __launch_bounds__(256) void k_build_cols(const float* __restrict__ peps,
                                                    float* __restrict__ ws) {
  __shared__ float p01[4096], p23[4096];
  int bid = blockIdx.x, t = threadIdx.x;
  if (bid == 0) {  // zero barrier tree (visible to k_gates via kernel boundary)
    int* c = (int*)(ws + CNTO);
    for (int e = t; e < 1088; e += 256) c[e] = 0;
  }
  if (bid < 384) {
    int col = 1 + (bid >> 7);
    int part = bid & 127;
#pragma unroll
    for (int k = 0; k < 16; ++k) {
      int e = k * 256 + t;
      int r12 = e & 15, l12 = (e >> 4) & 15, d2 = (e >> 8) & 3, p = e >> 10;
      int l1 = l12 >> 2, l2 = l12 & 3, r1 = r12 >> 2, r2 = r12 & 3;
      float s01 = 0.f, s23 = 0.f;
#pragma unroll
      for (int d = 0; d < 4; ++d) {
        s01 += peps[PIDX(0, col, (p >> 1), 0, d, l1, r1)] *
               peps[PIDX(1, col, (p & 1), d, d2, l2, r2)];
        s23 += peps[PIDX(2, col, (p >> 1), d2, d, l1, r1)] *
               peps[PIDX(3, col, (p & 1), d, 0, l2, r2)];
      }
      p01[e] = s01;
      p23[e] = s23;
    }
    __syncthreads();
    const int coloffs[3] = {COL1, COL2, COL3};
    float* out = ws + coloffs[col - 1];
#pragma unroll
    for (int k = 0; k < 8; ++k) {
      int eq = part * 8192 + (k * 256 + t) * 4;
      int r34b = eq & 15;
      int r12 = (eq >> 4) & 15, l34 = (eq >> 8) & 15, l12 = (eq >> 12) & 15;
      int p = eq >> 16;
      int pa = p >> 2, pb = p & 3;
      float4 acc = {0.f, 0.f, 0.f, 0.f};
#pragma unroll
      for (int d2 = 0; d2 < 4; ++d2) {
        float a01 = p01[((((pa * 4 + d2) << 4) | l12) << 4) | r12];
        const float4 b4 =
            *(const float4*)&p23[((((pb * 4 + d2) << 4) | l34) << 4) | r34b];
        acc.x += a01 * b4.x;
        acc.y += a01 * b4.y;
        acc.z += a01 * b4.z;
        acc.w += a01 * b4.w;
      }
      *(float4*)&out[eq] = acc;
    }
  } else {
    int col = (bid == 384) ? 0 : 4;
    const int lsh = (col == 0) ? 0 : 2;
    const int rsh = (col == 4) ? 0 : 2;
    const int ldim = 1 << lsh, rdim = 1 << rsh;
    const int LLB = 2 * lsh, RRB = 2 * rsh;
    const int LL = 1 << LLB, RR = 1 << RRB;
    int n12 = (LL * RR) << 4;
    for (int e = t; e < n12; e += 256) {
      int r12 = e & (RR - 1);
      int l12 = (e >> RRB) & (LL - 1);
      int d2 = (e >> (RRB + LLB)) & 3;
      int p = e >> (RRB + LLB + 2);
      int l1 = l12 >> lsh, l2 = l12 & (ldim - 1);
      int r1 = r12 >> rsh, r2 = r12 & (rdim - 1);
      float s01 = 0.f, s23 = 0.f;
      for (int d = 0; d < 4; ++d) {
        s01 += peps[PIDX(0, col, (p >> 1), 0, d, l1, r1)] *
               peps[PIDX(1, col, (p & 1), d, d2, l2, r2)];
        s23 += peps[PIDX(2, col, (p >> 1), d2, d, l1, r1)] *
               peps[PIDX(3, col, (p & 1), d, 0, l2, r2)];
      }
      p01[e] = s01;
      p23[e] = s23;
    }
    __syncthreads();
    const int LB = 2 * LLB, RB = 2 * RRB;
    int total = 16 << (LB + RB);  // 4096
    float* out = ws + ((col == 0) ? COL0 : COL4);
    for (int e = t; e < total; e += 256) {
      int r = e & ((1 << RB) - 1);
      int l = (e >> RB) & ((1 << LB) - 1);
      int p = e >> (RB + LB);
      int r34 = r & (RR - 1), r12 = r >> RRB;
      int l34 = l & (LL - 1), l12 = l >> LLB;
      int pa = p >> 2, pb = p & 3;
      float s = 0.f;
      for (int d2 = 0; d2 < 4; ++d2) {
        s += p01[((((pa * 4 + d2) << LLB) | l12) << RRB) | r12] *
             p23[((((pb * 4 + d2) << LLB) | l34) << RRB) | r34];
      }
      out[e] = s;
    }
  }
}

// ------------------- M01 / M34T (edge-pair contractions) -------------------
__global__ __launch_bounds__(256) void k_small(const float* __restrict__ ws,
                                               float* __restrict__ m01,
                                               float* __restrict__ m34t) {
  __shared__ float c3buf[4112], c4buf[4112];
  int t = threadIdx.x;
  if (blockIdx.x < 64) {
    int c1 = blockIdx.x >> 2, q = blockIdx.x & 3;
    int r2l = t & 63, c0g = t >> 6;  // wave-uniform c0 group (4 c0 each)
    int R2 = q * 64 + r2l;
    const float* col0 = ws + COL0;
    const float* col1 = ws + COL1;
    float a0 = 0.f, a1 = 0.f, a2 = 0.f, a3 = 0.f;
    for (int R1 = 0; R1 < 256; ++R1) {
      float bv = col1[(c1 * 256 + R1) * 256 + R2];  // coalesced
      a0 += col0[(c0g * 4 + 0) * 256 + R1] * bv;    // uniform -> s_load
      a1 += col0[(c0g * 4 + 1) * 256 + R1] * bv;
      a2 += col0[(c0g * 4 + 2) * 256 + R1] * bv;
      a3 += col0[(c0g * 4 + 3) * 256 + R1] * bv;
    }
    m01[((c0g * 4 + 0) * 16 + c1) * 256 + R2] = a0;  // coalesced
    m01[((c0g * 4 + 1) * 16 + c1) * 256 + R2] = a1;
    m01[((c0g * 4 + 2) * 16 + c1) * 256 + R2] = a2;
    m01[((c0g * 4 + 3) * 16 + c1) * 256 + R2] = a3;
  } else {
    int L3 = blockIdx.x - 64;  // 0..255
    const float* col3 = ws + COL3;
    const float* col4 = ws + COL4;
    for (int e = t; e < 4096; e += 256) {
      c4buf[(e >> 8) * 257 + (e & 255)] = col4[e];
      c3buf[(e >> 8) * 257 + (e & 255)] =
          col3[(e >> 8) * 65536 + L3 * 256 + (e & 255)];
    }
    __syncthreads();
    int c3 = t >> 4, c4 = t & 15;
    float acc = 0.f;
    for (int B = 0; B < 256; ++B)
      acc += c3buf[c3 * 257 + B] * c4buf[c4 * 257 + B];
    m34t[L3 * 256 + t] = acc;
  }
}

// ---------------- T012[c2][c01][R3] = M01 x Col2 ---------------------------
__global__ __launch_bounds__(256) void k_t012(const float* __restrict__ m01,
                                              const float* __restrict__ col2,
                                              float* __restrict__ t012) {
  __shared__ float A[4096];  // [i=16][R2=256]
  int t = threadIdx.x;       // R3
  int c2 = blockIdx.x & 15, tg = blockIdx.x >> 4;
#pragma unroll
  for (int k = 0; k < 4; ++k)
    *(float4*)&A[(k * 256 + t) * 4] =
        *(const float4*)&m01[tg * 4096 + (k * 256 + t) * 4];
  __syncthreads();
  float acc[16] = {};
  for (int R2 = 0; R2 < 256; R2 += 4) {
    float b0 = col2[c2 * 65536 + (R2 + 0) * 256 + t];
    float b1 = col2[c2 * 65536 + (R2 + 1) * 256 + t];
    float b2 = col2[c2 * 65536 + (R2 + 2) * 256 + t];
    float b3 = col2[c2 * 65536 + (R2 + 3) * 256 + t];
#pragma unroll
    for (int i = 0; i < 16; ++i) {
      float4 a4 = *(const float4*)&A[i * 256 + R2];  // broadcast b128
      acc[i] += a4.x * b0 + a4.y * b1 + a4.z * b2 + a4.w * b3;
    }
  }
#pragma unroll
  for (int i = 0; i < 16; ++i)
    t012[c2 * 65536 + (tg * 16 + i) * 256 + t] = acc[i];  // coalesced
}

// ---------------- psi = T012 x M34T, emitted in GATE layout ----------------
__global__ __launch_bounds__(256) void k_psi0(const float* __restrict__ t012,
                                              const float* __restrict__ m34t,
                                              float* __restrict__ psi) {
  __shared__ float A[4096];  // [i=c2=16][L3=256]
  __shared__ float S[4112];  // [c2=16][c34=257-padded]
  int t = threadIdx.x;       // c34 (and L3 for staging)
  int tg = blockIdx.x;       // c01
#pragma unroll
  for (int i = 0; i < 16; ++i)
    A[i * 256 + t] = t012[i * 65536 + tg * 256 + t];  // coalesced 1KB chunks
  __syncthreads();
  float acc[16] = {};
  for (int L3 = 0; L3 < 256; L3 += 4) {
    float b0 = m34t[(L3 + 0) * 256 + t];
    float b1 = m34t[(L3 + 1) * 256 + t];
    float b2 = m34t[(L3 + 2) * 256 + t];
    float b3 = m34t[(L3 + 3) * 256 + t];
#pragma unroll
    for (int i = 0; i < 16; ++i) {
      float4 a4 = *(const float4*)&A[i * 256 + L3];  // broadcast b128
      acc[i] += a4.x * b0 + a4.y * b1 + a4.z * b2 + a4.w * b3;
    }
  }
#pragma unroll
  for (int i = 0; i < 16; ++i) S[i * 257 + t] = acc[i];
  __syncthreads();
  // store: u = c3*16 + c2, v = c4 -> 64B runs (c2 lane-consecutive)
  int c3 = t >> 4, c2 = t & 15;
  int base = c3 * 65536 + (tg >> 4) * 256 + (tg & 15) * 16 + c2;
#pragma unroll
  for (int v = 0; v < 16; ++v)
    psi[base + v * 4096] = S[c2 * 257 + c3 * 16 + v];
}

// ---------------- register-level 2-qubit gate ------------------------------
template <int NB, int HI, int LO>
__device__ __forceinline__ void gate2(float* x, const float* __restrict__ g) {
  constexpr int H = 1 << HI, L = 1 << LO, N = 1 << NB;
#pragma unroll
  for (int o = 0; o < N; ++o) {
    if (o & (H | L)) continue;
    float v0 = x[o], v1 = x[o + L], v2 = x[o + H], v3 = x[o + H + L];
    x[o]         = g[0]  * v0 + g[1]  * v1 + g[2]  * v2 + g[3]  * v3;
    x[o + L]     = g[4]  * v0 + g[5]  * v1 + g[6]  * v2 + g[7]  * v3;
    x[o + H]     = g[8]  * v0 + g[9]  * v1 + g[10] * v2 + g[11] * v3;
    x[o + H + L] = g[12] * v0 + g[13] * v1 + g[14] * v2 + g[15] * v3;
  }
}

// V column transform: 4-bit nibble, x bit3 = row 0; bonds (3,2),(2,1),(1,0)
template <int ST>
__device__ __forceinline__ void vxf(float* s, const float* __restrict__ g, int b) {
  float x[16];
#pragma unroll
  for (int m = 0; m < 16; ++m) x[m] = s[PAD(b + m * ST)];
  gate2<4, 3, 2>(x, g);
  gate2<4, 2, 1>(x, g);
  gate2<4, 1, 0>(x, g);
#pragma unroll
  for (int m = 0; m < 16; ++m) s[PAD(b + m * ST)] = x[m];
}

// Bond-pair round (512 threads, 1 group each): gate on (B2,B1) then (B1,B0).
template <int B2, int B1, int B0>
__device__ __forceinline__ void bondpair(float* s, const float* __restrict__ g,
                                         int t) {
  constexpr int MASK = (1 << B2) | (1 << B1) | (1 << B0);
  int b = 0, rem = t;
#pragma unroll
  for (int p = 0; p < 12; ++p) {
    if (!((MASK >> p) & 1)) {
      b |= (rem & 1) << p;
      rem >>= 1;
    }
  }
  float x[8];
#pragma unroll
  for (int m = 0; m < 8; ++m) {
    int off = ((m >> 2) & 1) * (1 << B2) + ((m >> 1) & 1) * (1 << B1) +
              (m & 1) * (1 << B0);
    x[m] = s[PAD(b + off)];
  }
  gate2<3, 2, 1>(x, g);  // bond (B2, B1)
  gate2<3, 1, 0>(x, g);  // bond (B1, B0)
#pragma unroll
  for (int m = 0; m < 8; ++m) {
    int off = ((m >> 2) & 1) * (1 << B2) + ((m >> 1) & 1) * (1 << B1) +
              (m & 1) * (1 << B0);
    s[PAD(b + off)] = x[m];
  }
}

// ---------------- 16B coherent-point psi access (bypass L1+L2) -------------
__device__ __forceinline__ void cohload2(const float* p0, const float* p1,
                                         v4f& a, v4f& b) {
  asm volatile(
      "global_load_dwordx4 %0, %2, off sc0 sc1\n\t"
      "global_load_dwordx4 %1, %3, off sc0 sc1\n\t"
      "s_waitcnt vmcnt(0)"
      : "=&v"(a), "=&v"(b)
      : "v"(p0), "v"(p1)
      : "memory");
}
__device__ __forceinline__ void cohstore(float* p, v4f v) {
  asm volatile("global_store_dwordx4 %0, %1, off sc0 sc1"
               :
               : "v"(p), "v"(v)
               : "memory");
}
__device__ __forceinline__ void vmdrain() {
  asm volatile("s_waitcnt vmcnt(0)" ::: "memory");
}

// ---------------- two-level fence-free grid barrier ------------------------
// Tree: 16 group counters (256B apart) + root. All relaxed agent atomics.
// Correct because ALL shared data (psi) moves via coherent-point accesses:
// no L2-dirty/stale state exists, so no wbl2/inv fences are needed.
// vmdrain() orders this wave's asm psi stores before the arrive RMW.
__device__ __forceinline__ void gridbar(int* cnts, int gen) {
  vmdrain();        // asm stores are untracked by the compiler: drain manually
  __syncthreads();  // all waves' stores completed at coherent point
  if (threadIdx.x == 0) {
    int* gc = cnts + (blockIdx.x >> 4) * 64;
    int* root = cnts + 1024;
    int prev = __hip_atomic_fetch_add(gc, 1, __ATOMIC_RELAXED,
                                      __HIP_MEMORY_SCOPE_AGENT);
    if ((prev & 15) == 15)  // last of the 16 blocks in this group
      __hip_atomic_fetch_add(root, 1, __ATOMIC_RELAXED,
                             __HIP_MEMORY_SCOPE_AGENT);
    while (__hip_atomic_load(root, __ATOMIC_RELAXED,
                             __HIP_MEMORY_SCOPE_AGENT) < gen * 16) {
      __builtin_amdgcn_s_sleep(2);
    }
  }
  __syncthreads();
}

// ---------------- persistent gate loop: 5 x (P1, P2), 9 barriers -----------
__global__ __launch_bounds__(512) void k_gates(float* __restrict__ psi,
                                               const float* __restrict__ gate,
                                               const int* __restrict__ x,
                                               float* __restrict__ out,
                                               int* __restrict__ cnt) {
  __shared__ float s[5120];
  float g[16];
#pragma unroll
  for (int i = 0; i < 16; ++i) g[i] = gate[i];
  const int t = threadIdx.x;  // 512
  const int b = blockIdx.x;   // 256
  int gen = 0;

  for (int it = 0; it < 5; ++it) {
    // ---- P1: G2_01, G2_12, M16_0, M16_1. slab = low 12 bits, o = b -------
    {
      int f0 = t * 4, f1 = (512 + t) * 4;
      v4f a, c;
      cohload2(psi + b * 4096 + f0, psi + b * 4096 + f1, a, c);
      *(v4f*)(s + PAD(f0)) = a;
      *(v4f*)(s + PAD(f1)) = c;
    }
    __syncthreads();
    bondpair<8, 4, 0>(s, g, t);
    __syncthreads();
    bondpair<9, 5, 1>(s, g, t);
    __syncthreads();
    bondpair<10, 6, 2>(s, g, t);
    __syncthreads();
    bondpair<11, 7, 3>(s, g, t);
    __syncthreads();
    if (t < 256) vxf<256>(s, g, t);                          // M16_0
    __syncthreads();
    if (t < 256) vxf<16>(s, g, ((t >> 4) << 8) | (t & 15));  // M16_1
    __syncthreads();
    {
      int f0 = t * 4, f1 = (512 + t) * 4;
      cohstore(psi + b * 4096 + f0, *(const v4f*)(s + PAD(f0)));
      cohstore(psi + b * 4096 + f1, *(const v4f*)(s + PAD(f1)));
    }
    ++gen;
    gridbar(cnt, gen);

    // ---- P2: G2_23, G2_34, M16_2..4. slab = bits {19..12,3..0}, o = b ----
    {
      int f0 = t * 4, f1 = (512 + t) * 4;
      int a0 = (f0 >> 8) * 65536 + ((f0 >> 4) & 15) * 4096 + b * 16 + (f0 & 15);
      int a1 = (f1 >> 8) * 65536 + ((f1 >> 4) & 15) * 4096 + b * 16 + (f1 & 15);
      v4f a, c;
      cohload2(psi + a0, psi + a1, a, c);
      *(v4f*)(s + PAD(f0)) = a;
      *(v4f*)(s + PAD(f1)) = c;
    }
    __syncthreads();
    bondpair<0, 8, 4>(s, g, t);
    __syncthreads();
    bondpair<1, 9, 5>(s, g, t);
    __syncthreads();
    bondpair<2, 10, 6>(s, g, t);
    __syncthreads();
    bondpair<3, 11, 7>(s, g, t);
    __syncthreads();
    if (t < 256) vxf<1>(s, g, t * 16);                       // M16_2
    __syncthreads();
    if (t < 256) vxf<256>(s, g, t);                          // M16_3
    __syncthreads();
    if (t < 256) vxf<16>(s, g, ((t >> 4) << 8) | (t & 15));  // M16_4
    __syncthreads();
    if (it == 4) {
      if (t < 64) {
        int idx = 0;
#pragma unroll
        for (int q = 0; q < 20; ++q) {
          int i = q / 5, j = q % 5;
          int pos = (j == 0) ? (11 - i)
                   : (j == 1) ? (7 - i)
                   : (j == 2) ? (3 - i)
                   : (j == 3) ? (19 - i)
                              : (15 - i);
          idx |= x[t * 20 + q] << pos;
        }
        if (((idx >> 4) & 255) == b) {
          int local = ((idx >> 16) & 15) * 256 + ((idx >> 12) & 15) * 16 +
                      (idx & 15);
          out[t] = s[PAD(local)];
        }
      }
    } else {
      int f0 = t * 4, f1 = (512 + t) * 4;
      int a0 = (f0 >> 8) * 65536 + ((f0 >> 4) & 15) * 4096 + b * 16 + (f0 & 15);
      int a1 = (f1 >> 8) * 65536 + ((f1 >> 4) & 15) * 4096 + b * 16 + (f1 & 15);
      cohstore(psi + a0, *(const v4f*)(s + PAD(f0)));
      cohstore(psi + a1, *(const v4f*)(s + PAD(f1)));
      ++gen;
      gridbar(cnt, gen);
    }
  }
}

// ---------------------------------------------------------------------------
extern "C" void kernel_launch(void* const* d_in, const int* in_sizes, int n_in,
                              void* d_out, int out_size, void* d_ws, size_t ws_size,
                              hipStream_t stream) {
  const int* x = (const int*)d_in[0];
  const float* peps = (const float*)d_in[1];
  const float* gate = (const float*)d_in[2];
  float* ws = (float*)d_ws;
  float* psi = ws + PSIO;
  float* out = (float*)d_out;
  int* cnt = (int*)(ws + CNTO);

  k_build_cols<<<386, 256, 0, stream>>>(peps, ws);
  k_small<<<320, 256, 0, stream>>>(ws, ws + M01TO, ws + M34TO);
  k_t012<<<256, 256, 0, stream>>>(ws + M01TO, ws + COL2, ws + T12TO);
  k_psi0<<<256, 256, 0, stream>>>(ws + T12TO, ws + M34TO, psi);

  void* args[] = {(void*)&psi, (void*)&gate, (void*)&x, (void*)&out,
                  (void*)&cnt};
  hipLaunchCooperativeKernel((void*)k_gates, dim3(256), dim3(512), args, 0,
                             stream);
}

// Round 5
// 220.685 us; speedup vs baseline: 2.6756x; 1.1081x over previous
//
#include <hip/hip_runtime.h>

// ---------------------------------------------------------------------------
// PEPS 4x5, D=4, P=2, depth-5 gate sweeps, 64-point gather.
// Setup: 4 kernels (identical to 214us baseline).
// Gate loop: ONE persistent kernel, PLAIN launch (no cooperative API --
//   barrier is hand-rolled; co-residency by capacity: 256 blocks x 512 thr,
//   20.5KB LDS, 72 VGPR -> all blocks resident even at 2 blocks/CU).
//   - psi accessed ONLY via 16B coherent loads/stores (global_*_dwordx4
//     sc0 sc1: to the coherent point; L2 never holds dirty/stale psi lines).
//   - grid barrier = two-level arrival tree (16 groups x 16 + root) of
//     relaxed agent atomics. NO threadfence => NO buffer_wbl2 L2 walks.
//     Explicit s_waitcnt vmcnt(0) before arrive (asm stores untracked).
// Gate layout: psi idx = c3<<16 | c4<<12 | c0<<8 | c1<<4 | c2.
// ---------------------------------------------------------------------------

#define PAD(i) ((i) + (((i) >> 4) << 2))   // +4 floats per 16 -> LDS bank spread
#define PIDX(i,j,p,u,d,l,r) (((((((i)*5+(j))*2+(p))*4+(u))*4+(d))*4+(l))*4+(r))

typedef float v4f __attribute__((ext_vector_type(4)));

// workspace float offsets
static constexpr int COL0  = 0;                    // [16][256]
static constexpr int COL1  = 4096;                 // [16][256][256]
static constexpr int COL2  = COL1 + 1048576;
static constexpr int COL3  = COL2 + 1048576;
static constexpr int COL4  = COL3 + 1048576;       // [16][256]
static constexpr int M01TO = COL4 + 4096;          // [c01=256][R2=256]
static constexpr int M34TO = M01TO + 65536;        // [L3=256][c34=256]
static constexpr int T12TO = M34TO + 65536;        // [c2=16][c01=256][R3=256]
static constexpr int PSIO  = T12TO + 1048576;      // [2^20] gate layout
static constexpr int CNTO  = PSIO + 1048576;       // barrier tree: 17 lines x 64 ints

// --------------------------- column tensors --------------------------------
__global__ __launch_bounds__(256) void k_build_cols(const float* __restrict__ peps,
                                                    float* __restrict__ ws) {
  __shared__ float p01[4096], p23[4096];
  int bid = blockIdx.x, t = threadIdx.x;
  if (bid == 0) {  // zero barrier tree (visible to k_gates via kernel boundary)
    int* c = (int*)(ws + CNTO);
    for (int e = t; e < 1088; e += 256) c[e] = 0;
  }
  if (bid < 384) {
    int col = 1 + (bid >> 7);
    int part = bid & 127;
#pragma unroll
    for (int k = 0; k < 16; ++k) {
      int e = k * 256 + t;
      int r12 = e & 15, l12 = (e >> 4) & 15, d2 = (e >> 8) & 3, p = e >> 10;
      int l1 = l12 >> 2, l2 = l12 & 3, r1 = r12 >> 2, r2 = r12 & 3;
      float s01 = 0.f, s23 = 0.f;
#pragma unroll
      for (int d = 0; d < 4; ++d) {
        s01 += peps[PIDX(0, col, (p >> 1), 0, d, l1, r1)] *
               peps[PIDX(1, col, (p & 1), d, d2, l2, r2)];
        s23 += peps[PIDX(2, col, (p >> 1), d2, d, l1, r1)] *
               peps[PIDX(3, col, (p & 1), d, 0, l2, r2)];
      }
      p01[e] = s01;
      p23[e] = s23;
    }
    __syncthreads();
    const int coloffs[3] = {COL1, COL2, COL3};
    float* out = ws + coloffs[col - 1];
#pragma unroll
    for (int k = 0; k < 8; ++k) {
      int eq = part * 8192 + (k * 256 + t) * 4;
      int r34b = eq & 15;
      int r12 = (eq >> 4) & 15, l34 = (eq >> 8) & 15, l12 = (eq >> 12) & 15;
      int p = eq >> 16;
      int pa = p >> 2, pb = p & 3;
      float4 acc = {0.f, 0.f, 0.f, 0.f};
#pragma unroll
      for (int d2 = 0; d2 < 4; ++d2) {
        float a01 = p01[((((pa * 4 + d2) << 4) | l12) << 4) | r12];
        const float4 b4 =
            *(const float4*)&p23[((((pb * 4 + d2) << 4) | l34) << 4) | r34b];
        acc.x += a01 * b4.x;
        acc.y += a01 * b4.y;
        acc.z += a01 * b4.z;
        acc.w += a01 * b4.w;
      }
      *(float4*)&out[eq] = acc;
    }
  } else {
    int col = (bid == 384) ? 0 : 4;
    const int lsh = (col == 0) ? 0 : 2;
    const int rsh = (col == 4) ? 0 : 2;
    const int ldim = 1 << lsh, rdim = 1 << rsh;
    const int LLB = 2 * lsh, RRB = 2 * rsh;
    const int LL = 1 << LLB, RR = 1 << RRB;
    int n12 = (LL * RR) << 4;
    for (int e = t; e < n12; e += 256) {
      int r12 = e & (RR - 1);
      int l12 = (e >> RRB) & (LL - 1);
      int d2 = (e >> (RRB + LLB)) & 3;
      int p = e >> (RRB + LLB + 2);
      int l1 = l12 >> lsh, l2 = l12 & (ldim - 1);
      int r1 = r12 >> rsh, r2 = r12 & (rdim - 1);
      float s01 = 0.f, s23 = 0.f;
      for (int d = 0; d < 4; ++d) {
        s01 += peps[PIDX(0, col, (p >> 1), 0, d, l1, r1)] *
               peps[PIDX(1, col, (p & 1), d, d2, l2, r2)];
        s23 += peps[PIDX(2, col, (p >> 1), d2, d, l1, r1)] *
               peps[PIDX(3, col, (p & 1), d, 0, l2, r2)];
      }
      p01[e] = s01;
      p23[e] = s23;
    }
    __syncthreads();
    const int LB = 2 * LLB, RB = 2 * RRB;
    int total = 16 << (LB + RB);  // 4096
    float* out = ws + ((col == 0) ? COL0 : COL4);
    for (int e = t; e < total; e += 256) {
      int r = e & ((1 << RB) - 1);
      int l = (e >> RB) & ((1 << LB) - 1);
      int p = e >> (RB + LB);
      int r34 = r & (RR - 1), r12 = r >> RRB;
      int l34 = l & (LL - 1), l12 = l >> LLB;
      int pa = p >> 2, pb = p & 3;
      float s = 0.f;
      for (int d2 = 0; d2 < 4; ++d2) {
        s += p01[((((pa * 4 + d2) << LLB) | l12) << RRB) | r12] *
             p23[((((pb * 4 + d2) << LLB) | l34) << RRB) | r34];
      }
      out[e] = s;
    }
  }
}

// ------------------- M01 / M34T (edge-pair contractions) -------------------
__global__ __launch_bounds__(256) void k_small(const float* __restrict__ ws,
                                               float* __restrict__ m01,
                                               float* __restrict__ m34t) {
  __shared__ float c3buf[4112], c4buf[4112];
  int t = threadIdx.x;
  if (blockIdx.x < 64) {
    int c1 = blockIdx.x >> 2, q = blockIdx.x & 3;
    int r2l = t & 63, c0g = t >> 6;  // wave-uniform c0 group (4 c0 each)
    int R2 = q * 64 + r2l;
    const float* col0 = ws + COL0;
    const float* col1 = ws + COL1;
    float a0 = 0.f, a1 = 0.f, a2 = 0.f, a3 = 0.f;
    for (int R1 = 0; R1 < 256; ++R1) {
      float bv = col1[(c1 * 256 + R1) * 256 + R2];  // coalesced
      a0 += col0[(c0g * 4 + 0) * 256 + R1] * bv;    // uniform -> s_load
      a1 += col0[(c0g * 4 + 1) * 256 + R1] * bv;
      a2 += col0[(c0g * 4 + 2) * 256 + R1] * bv;
      a3 += col0[(c0g * 4 + 3) * 256 + R1] * bv;
    }
    m01[((c0g * 4 + 0) * 16 + c1) * 256 + R2] = a0;  // coalesced
    m01[((c0g * 4 + 1) * 16 + c1) * 256 + R2] = a1;
    m01[((c0g * 4 + 2) * 16 + c1) * 256 + R2] = a2;
    m01[((c0g * 4 + 3) * 16 + c1) * 256 + R2] = a3;
  } else {
    int L3 = blockIdx.x - 64;  // 0..255
    const float* col3 = ws + COL3;
    const float* col4 = ws + COL4;
    for (int e = t; e < 4096; e += 256) {
      c4buf[(e >> 8) * 257 + (e & 255)] = col4[e];
      c3buf[(e >> 8) * 257 + (e & 255)] =
          col3[(e >> 8) * 65536 + L3 * 256 + (e & 255)];
    }
    __syncthreads();
    int c3 = t >> 4, c4 = t & 15;
    float acc = 0.f;
    for (int B = 0; B < 256; ++B)
      acc += c3buf[c3 * 257 + B] * c4buf[c4 * 257 + B];
    m34t[L3 * 256 + t] = acc;
  }
}

// ---------------- T012[c2][c01][R3] = M01 x Col2 ---------------------------
__global__ __launch_bounds__(256) void k_t012(const float* __restrict__ m01,
                                              const float* __restrict__ col2,
                                              float* __restrict__ t012) {
  __shared__ float A[4096];  // [i=16][R2=256]
  int t = threadIdx.x;       // R3
  int c2 = blockIdx.x & 15, tg = blockIdx.x >> 4;
#pragma unroll
  for (int k = 0; k < 4; ++k)
    *(float4*)&A[(k * 256 + t) * 4] =
        *(const float4*)&m01[tg * 4096 + (k * 256 + t) * 4];
  __syncthreads();
  float acc[16] = {};
  for (int R2 = 0; R2 < 256; R2 += 4) {
    float b0 = col2[c2 * 65536 + (R2 + 0) * 256 + t];
    float b1 = col2[c2 * 65536 + (R2 + 1) * 256 + t];
    float b2 = col2[c2 * 65536 + (R2 + 2) * 256 + t];
    float b3 = col2[c2 * 65536 + (R2 + 3) * 256 + t];
#pragma unroll
    for (int i = 0; i < 16; ++i) {
      float4 a4 = *(const float4*)&A[i * 256 + R2];  // broadcast b128
      acc[i] += a4.x * b0 + a4.y * b1 + a4.z * b2 + a4.w * b3;
    }
  }
#pragma unroll
  for (int i = 0; i < 16; ++i)
    t012[c2 * 65536 + (tg * 16 + i) * 256 + t] = acc[i];  // coalesced
}

// ---------------- psi = T012 x M34T, emitted in GATE layout ----------------
__global__ __launch_bounds__(256) void k_psi0(const float* __restrict__ t012,
                                              const float* __restrict__ m34t,
                                              float* __restrict__ psi) {
  __shared__ float A[4096];  // [i=c2=16][L3=256]
  __shared__ float S[4112];  // [c2=16][c34=257-padded]
  int t = threadIdx.x;       // c34 (and L3 for staging)
  int tg = blockIdx.x;       // c01
#pragma unroll
  for (int i = 0; i < 16; ++i)
    A[i * 256 + t] = t012[i * 65536 + tg * 256 + t];  // coalesced 1KB chunks
  __syncthreads();
  float acc[16] = {};
  for (int L3 = 0; L3 < 256; L3 += 4) {
    float b0 = m34t[(L3 + 0) * 256 + t];
    float b1 = m34t[(L3 + 1) * 256 + t];
    float b2 = m34t[(L3 + 2) * 256 + t];
    float b3 = m34t[(L3 + 3) * 256 + t];
#pragma unroll
    for (int i = 0; i < 16; ++i) {
      float4 a4 = *(const float4*)&A[i * 256 + L3];  // broadcast b128
      acc[i] += a4.x * b0 + a4.y * b1 + a4.z * b2 + a4.w * b3;
    }
  }
#pragma unroll
  for (int i = 0; i < 16; ++i) S[i * 257 + t] = acc[i];
  __syncthreads();
  // store: u = c3*16 + c2, v = c4 -> 64B runs (c2 lane-consecutive)
  int c3 = t >> 4, c2 = t & 15;
  int base = c3 * 65536 + (tg >> 4) * 256 + (tg & 15) * 16 + c2;
#pragma unroll
  for (int v = 0; v < 16; ++v)
    psi[base + v * 4096] = S[c2 * 257 + c3 * 16 + v];
}

// ---------------- register-level 2-qubit gate ------------------------------
template <int NB, int HI, int LO>
__device__ __forceinline__ void gate2(float* x, const float* __restrict__ g) {
  constexpr int H = 1 << HI, L = 1 << LO, N = 1 << NB;
#pragma unroll
  for (int o = 0; o < N; ++o) {
    if (o & (H | L)) continue;
    float v0 = x[o], v1 = x[o + L], v2 = x[o + H], v3 = x[o + H + L];
    x[o]         = g[0]  * v0 + g[1]  * v1 + g[2]  * v2 + g[3]  * v3;
    x[o + L]     = g[4]  * v0 + g[5]  * v1 + g[6]  * v2 + g[7]  * v3;
    x[o + H]     = g[8]  * v0 + g[9]  * v1 + g[10] * v2 + g[11] * v3;
    x[o + H + L] = g[12] * v0 + g[13] * v1 + g[14] * v2 + g[15] * v3;
  }
}

// V column transform: 4-bit nibble, x bit3 = row 0; bonds (3,2),(2,1),(1,0)
template <int ST>
__device__ __forceinline__ void vxf(float* s, const float* __restrict__ g, int b) {
  float x[16];
#pragma unroll
  for (int m = 0; m < 16; ++m) x[m] = s[PAD(b + m * ST)];
  gate2<4, 3, 2>(x, g);
  gate2<4, 2, 1>(x, g);
  gate2<4, 1, 0>(x, g);
#pragma unroll
  for (int m = 0; m < 16; ++m) s[PAD(b + m * ST)] = x[m];
}

// Bond-pair round (512 threads, 1 group each): gate on (B2,B1) then (B1,B0).
template <int B2, int B1, int B0>
__device__ __forceinline__ void bondpair(float* s, const float* __restrict__ g,
                                         int t) {
  constexpr int MASK = (1 << B2) | (1 << B1) | (1 << B0);
  int b = 0, rem = t;
#pragma unroll
  for (int p = 0; p < 12; ++p) {
    if (!((MASK >> p) & 1)) {
      b |= (rem & 1) << p;
      rem >>= 1;
    }
  }
  float x[8];
#pragma unroll
  for (int m = 0; m < 8; ++m) {
    int off = ((m >> 2) & 1) * (1 << B2) + ((m >> 1) & 1) * (1 << B1) +
              (m & 1) * (1 << B0);
    x[m] = s[PAD(b + off)];
  }
  gate2<3, 2, 1>(x, g);  // bond (B2, B1)
  gate2<3, 1, 0>(x, g);  // bond (B1, B0)
#pragma unroll
  for (int m = 0; m < 8; ++m) {
    int off = ((m >> 2) & 1) * (1 << B2) + ((m >> 1) & 1) * (1 << B1) +
              (m & 1) * (1 << B0);
    s[PAD(b + off)] = x[m];
  }
}

// ---------------- 16B coherent-point psi access (bypass L1+L2) -------------
__device__ __forceinline__ void cohload2(const float* p0, const float* p1,
                                         v4f& a, v4f& b) {
  asm volatile(
      "global_load_dwordx4 %0, %2, off sc0 sc1\n\t"
      "global_load_dwordx4 %1, %3, off sc0 sc1\n\t"
      "s_waitcnt vmcnt(0)"
      : "=&v"(a), "=&v"(b)
      : "v"(p0), "v"(p1)
      : "memory");
}
__device__ __forceinline__ void cohstore(float* p, v4f v) {
  asm volatile("global_store_dwordx4 %0, %1, off sc0 sc1"
               :
               : "v"(p), "v"(v)
               : "memory");
}
__device__ __forceinline__ void vmdrain() {
  asm volatile("s_waitcnt vmcnt(0)" ::: "memory");
}

// ---------------- two-level fence-free grid barrier ------------------------
// Tree: 16 group counters (256B apart) + root. All relaxed agent atomics.
// Correct because ALL shared data (psi) moves via coherent-point accesses:
// no L2-dirty/stale state exists, so no wbl2/inv fences are needed.
// vmdrain() orders this wave's asm psi stores before the arrive RMW.
__device__ __forceinline__ void gridbar(int* cnts, int gen) {
  vmdrain();        // asm stores are untracked by the compiler: drain manually
  __syncthreads();  // all waves' stores completed at coherent point
  if (threadIdx.x == 0) {
    int* gc = cnts + (blockIdx.x >> 4) * 64;
    int* root = cnts + 1024;
    int prev = __hip_atomic_fetch_add(gc, 1, __ATOMIC_RELAXED,
                                      __HIP_MEMORY_SCOPE_AGENT);
    if ((prev & 15) == 15)  // last of the 16 blocks in this group
      __hip_atomic_fetch_add(root, 1, __ATOMIC_RELAXED,
                             __HIP_MEMORY_SCOPE_AGENT);
    while (__hip_atomic_load(root, __ATOMIC_RELAXED,
                             __HIP_MEMORY_SCOPE_AGENT) < gen * 16) {
      __builtin_amdgcn_s_sleep(2);
    }
  }
  __syncthreads();
}

// ---------------- persistent gate loop: 5 x (P1, P2), 9 barriers -----------
// Plain (non-cooperative) launch: barrier is hand-rolled; co-residency by
// capacity (256 blocks, 20.5KB LDS, 72 VGPR, 8 waves -> all resident).
__global__ __launch_bounds__(512) void k_gates(float* __restrict__ psi,
                                               const float* __restrict__ gate,
                                               const int* __restrict__ x,
                                               float* __restrict__ out,
                                               int* __restrict__ cnt) {
  __shared__ float s[5120];
  float g[16];
#pragma unroll
  for (int i = 0; i < 16; ++i) g[i] = gate[i];
  const int t = threadIdx.x;  // 512
  const int b = blockIdx.x;   // 256
  int gen = 0;

  for (int it = 0; it < 5; ++it) {
    // ---- P1: G2_01, G2_12, M16_0, M16_1. slab = low 12 bits, o = b -------
    {
      int f0 = t * 4, f1 = (512 + t) * 4;
      v4f a, c;
      cohload2(psi + b * 4096 + f0, psi + b * 4096 + f1, a, c);
      *(v4f*)(s + PAD(f0)) = a;
      *(v4f*)(s + PAD(f1)) = c;
    }
    __syncthreads();
    bondpair<8, 4, 0>(s, g, t);
    __syncthreads();
    bondpair<9, 5, 1>(s, g, t);
    __syncthreads();
    bondpair<10, 6, 2>(s, g, t);
    __syncthreads();
    bondpair<11, 7, 3>(s, g, t);
    __syncthreads();
    if (t < 256) vxf<256>(s, g, t);                          // M16_0
    __syncthreads();
    if (t < 256) vxf<16>(s, g, ((t >> 4) << 8) | (t & 15));  // M16_1
    __syncthreads();
    {
      int f0 = t * 4, f1 = (512 + t) * 4;
      cohstore(psi + b * 4096 + f0, *(const v4f*)(s + PAD(f0)));
      cohstore(psi + b * 4096 + f1, *(const v4f*)(s + PAD(f1)));
    }
    ++gen;
    gridbar(cnt, gen);

    // ---- P2: G2_23, G2_34, M16_2..4. slab = bits {19..12,3..0}, o = b ----
    {
      int f0 = t * 4, f1 = (512 + t) * 4;
      int a0 = (f0 >> 8) * 65536 + ((f0 >> 4) & 15) * 4096 + b * 16 + (f0 & 15);
      int a1 = (f1 >> 8) * 65536 + ((f1 >> 4) & 15) * 4096 + b * 16 + (f1 & 15);
      v4f a, c;
      cohload2(psi + a0, psi + a1, a, c);
      *(v4f*)(s + PAD(f0)) = a;
      *(v4f*)(s + PAD(f1)) = c;
    }
    __syncthreads();
    bondpair<0, 8, 4>(s, g, t);
    __syncthreads();
    bondpair<1, 9, 5>(s, g, t);
    __syncthreads();
    bondpair<2, 10, 6>(s, g, t);
    __syncthreads();
    bondpair<3, 11, 7>(s, g, t);
    __syncthreads();
    if (t < 256) vxf<1>(s, g, t * 16);                       // M16_2
    __syncthreads();
    if (t < 256) vxf<256>(s, g, t);                          // M16_3
    __syncthreads();
    if (t < 256) vxf<16>(s, g, ((t >> 4) << 8) | (t & 15));  // M16_4
    __syncthreads();
    if (it == 4) {
      if (t < 64) {
        int idx = 0;
#pragma unroll
        for (int q = 0; q < 20; ++q) {
          int i = q / 5, j = q % 5;
          int pos = (j == 0) ? (11 - i)
                   : (j == 1) ? (7 - i)
                   : (j == 2) ? (3 - i)
                   : (j == 3) ? (19 - i)
                              : (15 - i);
          idx |= x[t * 20 + q] << pos;
        }
        if (((idx >> 4) & 255) == b) {
          int local = ((idx >> 16) & 15) * 256 + ((idx >> 12) & 15) * 16 +
                      (idx & 15);
          out[t] = s[PAD(local)];
        }
      }
    } else {
      int f0 = t * 4, f1 = (512 + t) * 4;
      int a0 = (f0 >> 8) * 65536 + ((f0 >> 4) & 15) * 4096 + b * 16 + (f0 & 15);
      int a1 = (f1 >> 8) * 65536 + ((f1 >> 4) & 15) * 4096 + b * 16 + (f1 & 15);
      cohstore(psi + a0, *(const v4f*)(s + PAD(f0)));
      cohstore(psi + a1, *(const v4f*)(s + PAD(f1)));
      ++gen;
      gridbar(cnt, gen);
    }
  }
}

// ---------------------------------------------------------------------------
extern "C" void kernel_launch(void* const* d_in, const int* in_sizes, int n_in,
                              void* d_out, int out_size, void* d_ws, size_t ws_size,
                              hipStream_t stream) {
  const int* x = (const int*)d_in[0];
  const float* peps = (const float*)d_in[1];
  const float* gate = (const float*)d_in[2];
  float* ws = (float*)d_ws;
  float* psi = ws + PSIO;
  float* out = (float*)d_out;
  int* cnt = (int*)(ws + CNTO);

  k_build_cols<<<386, 256, 0, stream>>>(peps, ws);
  k_small<<<320, 256, 0, stream>>>(ws, ws + M01TO, ws + M34TO);
  k_t012<<<256, 256, 0, stream>>>(ws + M01TO, ws + COL2, ws + T12TO);
  k_psi0<<<256, 256, 0, stream>>>(ws + T12TO, ws + M34TO, psi);

  // Plain launch: no cooperative API needed (hand-rolled barrier).
  k_gates<<<256, 512, 0, stream>>>(psi, gate, x, out, cnt);
}

// Round 7
// 200.236 us; speedup vs baseline: 2.9488x; 1.1021x over previous
//
#include <hip/hip_runtime.h>

// ---------------------------------------------------------------------------
// PEPS 4x5, D=4, P=2, depth-5 gate sweeps, 64-point gather.
// ONE persistent kernel (plain launch), 13 fence-free tree barriers:
//   P1 cols -> P2 {M34T || M01} -> P3 t012 -> P4 psi0 -> 5x(G-P1, G-P2).
//
// COHERENCE PROTOCOL (lesson from r6 failure): the harness re-poisons the
// whole ws every iteration with cached stores; the fill's end-release leaves
// CLEAN POISON COPIES in L2. Coherent (sc0 sc1) write-through stores do NOT
// update those stale L2 lines, so ANY cached read of ws data may see poison.
// => EVERY ws access is coherent: stores via sc0 sc1 asm (16B where
//    contiguous), loads via __hip_atomic_load(AGENT, relaxed) (proven r3;
//    loads showed no FETCH amplification). Cached reads ONLY for true
//    inputs (peps, x, gate). Barriers then need no wbl2/inv fences.
// Hot streaming loops are source-level software-pipelined (32-wide
// double-buffered chunks, fully unrolled -> static reg indices).
// Gate layout: psi idx = c3<<16 | c4<<12 | c0<<8 | c1<<4 | c2.
// ---------------------------------------------------------------------------

#define PAD(i) ((i) + (((i) >> 4) << 2))   // +4 floats per 16 -> LDS bank spread
#define PIDX(i,j,p,u,d,l,r) (((((((i)*5+(j))*2+(p))*4+(u))*4+(d))*4+(l))*4+(r))

typedef float v4f __attribute__((ext_vector_type(4)));

// workspace float offsets
static constexpr int COL0  = 0;                    // [16][256]
static constexpr int COL1  = 4096;                 // [16][256][256]
static constexpr int COL2  = COL1 + 1048576;
static constexpr int COL3  = COL2 + 1048576;
static constexpr int COL4  = COL3 + 1048576;       // [16][256]
static constexpr int M01TO = COL4 + 4096;          // [c01=256][R2=256]
static constexpr int M34TO = M01TO + 65536;        // [L3=256][c34=256]
static constexpr int T12TO = M34TO + 65536;        // [c2=16][c01=256][R3=256]
static constexpr int PSIO  = T12TO + 1048576;      // [2^20] gate layout
static constexpr int CNTO  = PSIO + 1048576;       // barrier tree: 1088 ints

// ---------------- coherent-point access ------------------------------------
__device__ __forceinline__ float agl(const float* p) {      // coherent load
  return __hip_atomic_load(p, __ATOMIC_RELAXED, __HIP_MEMORY_SCOPE_AGENT);
}
__device__ __forceinline__ void cohload2(const float* p0, const float* p1,
                                         v4f& a, v4f& b) {
  asm volatile(
      "global_load_dwordx4 %0, %2, off sc0 sc1\n\t"
      "global_load_dwordx4 %1, %3, off sc0 sc1\n\t"
      "s_waitcnt vmcnt(0)"
      : "=&v"(a), "=&v"(b)
      : "v"(p0), "v"(p1)
      : "memory");
}
__device__ __forceinline__ void cohstore(float* p, v4f v) {
  asm volatile("global_store_dwordx4 %0, %1, off sc0 sc1"
               :
               : "v"(p), "v"(v)
               : "memory");
}
__device__ __forceinline__ void cohstore1(float* p, float v) {
  asm volatile("global_store_dword %0, %1, off sc0 sc1"
               :
               : "v"(p), "v"(v)
               : "memory");
}
__device__ __forceinline__ void vmdrain() {
  asm volatile("s_waitcnt vmcnt(0)" ::: "memory");
}

// ---------------- two-level fence-free grid barrier ------------------------
__device__ __forceinline__ void gridbar(int* cnts, int gen) {
  vmdrain();        // asm stores untracked by compiler: drain manually
  __syncthreads();  // all waves' stores completed at coherent point
  if (threadIdx.x == 0) {
    int* gc = cnts + (blockIdx.x >> 4) * 64;
    int* root = cnts + 1024;
    int prev = __hip_atomic_fetch_add(gc, 1, __ATOMIC_RELAXED,
                                      __HIP_MEMORY_SCOPE_AGENT);
    if ((prev & 15) == 15)
      __hip_atomic_fetch_add(root, 1, __ATOMIC_RELAXED,
                             __HIP_MEMORY_SCOPE_AGENT);
    while (__hip_atomic_load(root, __ATOMIC_RELAXED,
                             __HIP_MEMORY_SCOPE_AGENT) < gen * 16) {
      __builtin_amdgcn_s_sleep(2);
    }
  }
  __syncthreads();
}

// ---------------- register-level 2-qubit gate ------------------------------
template <int NB, int HI, int LO>
__device__ __forceinline__ void gate2(float* x, const float* __restrict__ g) {
  constexpr int H = 1 << HI, L = 1 << LO, N = 1 << NB;
#pragma unroll
  for (int o = 0; o < N; ++o) {
    if (o & (H | L)) continue;
    float v0 = x[o], v1 = x[o + L], v2 = x[o + H], v3 = x[o + H + L];
    x[o]         = g[0]  * v0 + g[1]  * v1 + g[2]  * v2 + g[3]  * v3;
    x[o + L]     = g[4]  * v0 + g[5]  * v1 + g[6]  * v2 + g[7]  * v3;
    x[o + H]     = g[8]  * v0 + g[9]  * v1 + g[10] * v2 + g[11] * v3;
    x[o + H + L] = g[12] * v0 + g[13] * v1 + g[14] * v2 + g[15] * v3;
  }
}

template <int ST>
__device__ __forceinline__ void vxf(float* s, const float* __restrict__ g, int b) {
  float x[16];
#pragma unroll
  for (int m = 0; m < 16; ++m) x[m] = s[PAD(b + m * ST)];
  gate2<4, 3, 2>(x, g);
  gate2<4, 2, 1>(x, g);
  gate2<4, 1, 0>(x, g);
#pragma unroll
  for (int m = 0; m < 16; ++m) s[PAD(b + m * ST)] = x[m];
}

template <int B2, int B1, int B0>
__device__ __forceinline__ void bondpair(float* s, const float* __restrict__ g,
                                         int t) {
  constexpr int MASK = (1 << B2) | (1 << B1) | (1 << B0);
  int b = 0, rem = t;
#pragma unroll
  for (int p = 0; p < 12; ++p) {
    if (!((MASK >> p) & 1)) {
      b |= (rem & 1) << p;
      rem >>= 1;
    }
  }
  float x[8];
#pragma unroll
  for (int m = 0; m < 8; ++m) {
    int off = ((m >> 2) & 1) * (1 << B2) + ((m >> 1) & 1) * (1 << B1) +
              (m & 1) * (1 << B0);
    x[m] = s[PAD(b + off)];
  }
  gate2<3, 2, 1>(x, g);  // bond (B2, B1)
  gate2<3, 1, 0>(x, g);  // bond (B1, B0)
#pragma unroll
  for (int m = 0; m < 8; ++m) {
    int off = ((m >> 2) & 1) * (1 << B2) + ((m >> 1) & 1) * (1 << B1) +
              (m & 1) * (1 << B0);
    s[PAD(b + off)] = x[m];
  }
}

// ---------------------------------------------------------------------------
// Grid 256 x 512, plain launch (co-residency by capacity: 32.9KB LDS).
// ---------------------------------------------------------------------------
__global__ __launch_bounds__(512) void k_all(const float* __restrict__ peps,
                                             const int* __restrict__ x,
                                             const float* __restrict__ gate,
                                             float* __restrict__ ws,
                                             float* __restrict__ out,
                                             int* __restrict__ cnt) {
  __shared__ float sm[8224];
  const int t = threadIdx.x;   // 0..511
  const int b = blockIdx.x;    // 0..255
  const int r3 = t & 255, half = t >> 8;
  float* psi = ws + PSIO;
  int gen = 0;

  // ===================== phase 1: column tensors ===========================
  if (b < 192) {
    float* p01 = sm;
    float* p23 = sm + 4096;
    int col = 1 + (b >> 6);
    int pb = b & 63;
#pragma unroll
    for (int k = 0; k < 8; ++k) {
      int e = k * 512 + t;
      int r12 = e & 15, l12 = (e >> 4) & 15, d2 = (e >> 8) & 3, p = e >> 10;
      int l1 = l12 >> 2, l2 = l12 & 3, r1 = r12 >> 2, r2 = r12 & 3;
      float s01 = 0.f, s23 = 0.f;
#pragma unroll
      for (int d = 0; d < 4; ++d) {
        s01 += peps[PIDX(0, col, (p >> 1), 0, d, l1, r1)] *
               peps[PIDX(1, col, (p & 1), d, d2, l2, r2)];
        s23 += peps[PIDX(2, col, (p >> 1), d2, d, l1, r1)] *
               peps[PIDX(3, col, (p & 1), d, 0, l2, r2)];
      }
      p01[e] = s01;
      p23[e] = s23;
    }
    __syncthreads();
    const int coloffs[3] = {COL1, COL2, COL3};
    float* outc = ws + coloffs[col - 1];
#pragma unroll
    for (int pp = 0; pp < 2; ++pp) {
      int part = pb * 2 + pp;
#pragma unroll
      for (int k = 0; k < 4; ++k) {
        int eq = part * 8192 + (k * 512 + t) * 4;
        int r34b = eq & 15;
        int r12 = (eq >> 4) & 15, l34 = (eq >> 8) & 15, l12 = (eq >> 12) & 15;
        int p = eq >> 16;
        int pa = p >> 2, pbv = p & 3;
        v4f acc = {0.f, 0.f, 0.f, 0.f};
#pragma unroll
        for (int d2 = 0; d2 < 4; ++d2) {
          float a01 = p01[((((pa * 4 + d2) << 4) | l12) << 4) | r12];
          const float4 b4 =
              *(const float4*)&p23[((((pbv * 4 + d2) << 4) | l34) << 4) | r34b];
          acc.x += a01 * b4.x;
          acc.y += a01 * b4.y;
          acc.z += a01 * b4.z;
          acc.w += a01 * b4.w;
        }
        cohstore(&outc[eq], acc);
      }
    }
  } else if (b < 194) {
    float* p01 = sm;
    float* p23 = sm + 4096;
    int col = (b == 192) ? 0 : 4;
    const int lsh = (col == 0) ? 0 : 2;
    const int rsh = (col == 4) ? 0 : 2;
    const int ldim = 1 << lsh, rdim = 1 << rsh;
    const int LLB = 2 * lsh, RRB = 2 * rsh;
    const int LL = 1 << LLB, RR = 1 << RRB;
    int n12 = (LL * RR) << 4;
    for (int e = t; e < n12; e += 512) {
      int r12 = e & (RR - 1);
      int l12 = (e >> RRB) & (LL - 1);
      int d2 = (e >> (RRB + LLB)) & 3;
      int p = e >> (RRB + LLB + 2);
      int l1 = l12 >> lsh, l2 = l12 & (ldim - 1);
      int r1 = r12 >> rsh, r2 = r12 & (rdim - 1);
      float s01 = 0.f, s23 = 0.f;
      for (int d = 0; d < 4; ++d) {
        s01 += peps[PIDX(0, col, (p >> 1), 0, d, l1, r1)] *
               peps[PIDX(1, col, (p & 1), d, d2, l2, r2)];
        s23 += peps[PIDX(2, col, (p >> 1), d2, d, l1, r1)] *
               peps[PIDX(3, col, (p & 1), d, 0, l2, r2)];
      }
      p01[e] = s01;
      p23[e] = s23;
    }
    __syncthreads();
    const int LB = 2 * LLB, RB = 2 * RRB;
    int total = 16 << (LB + RB);
    float* outc = ws + ((col == 0) ? COL0 : COL4);
    for (int e = t; e < total; e += 512) {
      int r = e & ((1 << RB) - 1);
      int l = (e >> RB) & ((1 << LB) - 1);
      int p = e >> (RB + LB);
      int r34 = r & (RR - 1), r12 = r >> RRB;
      int l34 = l & (LL - 1), l12 = l >> LLB;
      int pa = p >> 2, pbv = p & 3;
      float sacc = 0.f;
      for (int d2 = 0; d2 < 4; ++d2) {
        sacc += p01[((((pa * 4 + d2) << LLB) | l12) << RRB) | r12] *
                p23[((((pbv * 4 + d2) << LLB) | l34) << RRB) | r34];
      }
      cohstore1(&outc[e], sacc);
    }
  }
  gridbar(cnt, ++gen);

  // ============ phase 2: M34T (t<256) || M01 (t>=256, all blocks) ==========
  {
    float* c3buf = sm;           // [4112]
    float* c4buf = sm + 4112;    // [4112]
    const float* col3 = ws + COL3;
    const float* col4 = ws + COL4;
    const int L3 = b;
    if (t < 256) {
      float v3[16], v4[16];
#pragma unroll
      for (int k = 0; k < 16; ++k) {
        v4[k] = agl(&col4[k * 256 + t]);
        v3[k] = agl(&col3[k * 65536 + L3 * 256 + t]);
      }
#pragma unroll
      for (int k = 0; k < 16; ++k) {
        c4buf[k * 257 + t] = v4[k];
        c3buf[k * 257 + t] = v3[k];
      }
    } else {
      // M01[(c0*16+c1)*256 + R2] = sum_R1 col0[c0,R1]*col1[c1,R1,R2]
      int c0 = b >> 4, c1 = b & 15, R2 = t - 256;
      const float* col0 = ws + COL0 + c0 * 256;
      const float* col1 = ws + COL1 + c1 * 65536 + R2;
      float acc = 0.f;
      float a_[16], c_[16], an[16], cn[16];
#pragma unroll
      for (int j = 0; j < 16; ++j) {
        a_[j] = agl(&col0[j]);
        c_[j] = agl(&col1[j * 256]);
      }
#pragma unroll
      for (int ch = 0; ch < 16; ++ch) {
        if (ch < 15) {
#pragma unroll
          for (int j = 0; j < 16; ++j) {
            an[j] = agl(&col0[(ch + 1) * 16 + j]);
            cn[j] = agl(&col1[((ch + 1) * 16 + j) * 256]);
          }
        }
#pragma unroll
        for (int j = 0; j < 16; ++j) acc += a_[j] * c_[j];
        if (ch < 15) {
#pragma unroll
          for (int j = 0; j < 16; ++j) { a_[j] = an[j]; c_[j] = cn[j]; }
        }
      }
      cohstore1(&(ws + M01TO)[(c0 * 16 + c1) * 256 + R2], acc);
    }
    __syncthreads();
    if (t < 256) {
      int c3 = t >> 4, c4 = t & 15;
      float acc = 0.f;
      for (int B = 0; B < 256; ++B)
        acc += c3buf[c3 * 257 + B] * c4buf[c4 * 257 + B];
      cohstore1(&(ws + M34TO)[L3 * 256 + t], acc);
    }
  }
  gridbar(cnt, ++gen);

  // ===================== phase 3: T012 = M01 x Col2 ========================
  {
    float* A = sm;  // [4096] = [i=16][R2=256]
    const float* m01 = ws + M01TO;
    const float* col2 = ws + COL2;
    float* t012p = ws + T12TO;
    int c2 = b & 15, tg = b >> 4;
    {
      float tmp[8];
#pragma unroll
      for (int k = 0; k < 2; ++k)
#pragma unroll
        for (int j = 0; j < 4; ++j)
          tmp[k * 4 + j] = agl(&m01[tg * 4096 + (k * 512 + t) * 4 + j]);
#pragma unroll
      for (int k = 0; k < 2; ++k)
#pragma unroll
        for (int j = 0; j < 4; ++j)
          A[(k * 512 + t) * 4 + j] = tmp[k * 4 + j];
    }
    __syncthreads();
    float acc[8] = {};
    const float* cbase = col2 + c2 * 65536 + r3;
    float cur[32], nxt[32];
#pragma unroll
    for (int j = 0; j < 32; ++j) cur[j] = agl(&cbase[j * 256]);
#pragma unroll
    for (int ch = 0; ch < 8; ++ch) {
      if (ch < 7) {
#pragma unroll
        for (int j = 0; j < 32; ++j)
          nxt[j] = agl(&cbase[((ch + 1) * 32 + j) * 256]);
      }
#pragma unroll
      for (int jj = 0; jj < 32; jj += 4) {
        int R2 = ch * 32 + jj;
#pragma unroll
        for (int i = 0; i < 8; ++i) {
          float4 a4 = *(const float4*)&A[(half * 8 + i) * 256 + R2];
          acc[i] += a4.x * cur[jj] + a4.y * cur[jj + 1] + a4.z * cur[jj + 2] +
                    a4.w * cur[jj + 3];
        }
      }
      if (ch < 7) {
#pragma unroll
        for (int j = 0; j < 32; ++j) cur[j] = nxt[j];
      }
    }
#pragma unroll
    for (int i = 0; i < 8; ++i)
      cohstore1(&t012p[c2 * 65536 + (tg * 16 + half * 8 + i) * 256 + r3],
                acc[i]);
  }
  gridbar(cnt, ++gen);

  // ===================== phase 4: psi = T012 x M34T (gate layout) ==========
  {
    float* A = sm;            // [4096] = [i=c2=16][L3=256]
    float* S = sm + 4096;     // [4112] = [c2=16][c34=257-padded]
    const float* t012p = ws + T12TO;
    const float* m34t = ws + M34TO;
    int tg = b;
    {
      float tmp[8];
#pragma unroll
      for (int i = 0; i < 8; ++i)
        tmp[i] = agl(&t012p[(half * 8 + i) * 65536 + tg * 256 + r3]);
#pragma unroll
      for (int i = 0; i < 8; ++i) A[(half * 8 + i) * 256 + r3] = tmp[i];
    }
    __syncthreads();
    float acc[8] = {};
    const float* mbase = m34t + r3;
    float cur[32], nxt[32];
#pragma unroll
    for (int j = 0; j < 32; ++j) cur[j] = agl(&mbase[j * 256]);
#pragma unroll
    for (int ch = 0; ch < 8; ++ch) {
      if (ch < 7) {
#pragma unroll
        for (int j = 0; j < 32; ++j)
          nxt[j] = agl(&mbase[((ch + 1) * 32 + j) * 256]);
      }
#pragma unroll
      for (int jj = 0; jj < 32; jj += 4) {
        int L3 = ch * 32 + jj;
#pragma unroll
        for (int i = 0; i < 8; ++i) {
          float4 a4 = *(const float4*)&A[(half * 8 + i) * 256 + L3];
          acc[i] += a4.x * cur[jj] + a4.y * cur[jj + 1] + a4.z * cur[jj + 2] +
                    a4.w * cur[jj + 3];
        }
      }
      if (ch < 7) {
#pragma unroll
        for (int j = 0; j < 32; ++j) cur[j] = nxt[j];
      }
    }
#pragma unroll
    for (int i = 0; i < 8; ++i) S[(half * 8 + i) * 257 + r3] = acc[i];
    __syncthreads();
    int c3 = r3 >> 4, c2 = r3 & 15;
    int base = c3 * 65536 + (tg >> 4) * 256 + (tg & 15) * 16 + c2;
#pragma unroll
    for (int vv = 0; vv < 8; ++vv) {
      int v = half * 8 + vv;
      cohstore1(&psi[base + v * 4096], S[c2 * 257 + c3 * 16 + v]);
    }
  }
  gridbar(cnt, ++gen);

  // ===================== gate loop: 5 x (P1, P2) ===========================
  float g[16];
#pragma unroll
  for (int i = 0; i < 16; ++i) g[i] = gate[i];
  float* s = sm;

  for (int it = 0; it < 5; ++it) {
    // ---- P1: G2_01, G2_12, M16_0, M16_1. slab = low 12 bits, o = b -------
    {
      int f0 = t * 4, f1 = (512 + t) * 4;
      v4f a, c;
      cohload2(psi + b * 4096 + f0, psi + b * 4096 + f1, a, c);
      *(v4f*)(s + PAD(f0)) = a;
      *(v4f*)(s + PAD(f1)) = c;
    }
    __syncthreads();
    bondpair<8, 4, 0>(s, g, t);
    __syncthreads();
    bondpair<9, 5, 1>(s, g, t);
    __syncthreads();
    bondpair<10, 6, 2>(s, g, t);
    __syncthreads();
    bondpair<11, 7, 3>(s, g, t);
    __syncthreads();
    if (t < 256) vxf<256>(s, g, t);                          // M16_0
    __syncthreads();
    if (t < 256) vxf<16>(s, g, ((t >> 4) << 8) | (t & 15));  // M16_1
    __syncthreads();
    {
      int f0 = t * 4, f1 = (512 + t) * 4;
      cohstore(psi + b * 4096 + f0, *(const v4f*)(s + PAD(f0)));
      cohstore(psi + b * 4096 + f1, *(const v4f*)(s + PAD(f1)));
    }
    gridbar(cnt, ++gen);

    // ---- P2: G2_23, G2_34, M16_2..4. slab = bits {19..12,3..0}, o = b ----
    {
      int f0 = t * 4, f1 = (512 + t) * 4;
      int a0 = (f0 >> 8) * 65536 + ((f0 >> 4) & 15) * 4096 + b * 16 + (f0 & 15);
      int a1 = (f1 >> 8) * 65536 + ((f1 >> 4) & 15) * 4096 + b * 16 + (f1 & 15);
      v4f a, c;
      cohload2(psi + a0, psi + a1, a, c);
      *(v4f*)(s + PAD(f0)) = a;
      *(v4f*)(s + PAD(f1)) = c;
    }
    __syncthreads();
    bondpair<0, 8, 4>(s, g, t);
    __syncthreads();
    bondpair<1, 9, 5>(s, g, t);
    __syncthreads();
    bondpair<2, 10, 6>(s, g, t);
    __syncthreads();
    bondpair<3, 11, 7>(s, g, t);
    __syncthreads();
    if (t < 256) vxf<1>(s, g, t * 16);                       // M16_2
    __syncthreads();
    if (t < 256) vxf<256>(s, g, t);                          // M16_3
    __syncthreads();
    if (t < 256) vxf<16>(s, g, ((t >> 4) << 8) | (t & 15));  // M16_4
    __syncthreads();
    if (it == 4) {
      if (t < 64) {
        int idx = 0;
#pragma unroll
        for (int q = 0; q < 20; ++q) {
          int i = q / 5, j = q % 5;
          int pos = (j == 0) ? (11 - i)
                   : (j == 1) ? (7 - i)
                   : (j == 2) ? (3 - i)
                   : (j == 3) ? (19 - i)
                              : (15 - i);
          idx |= x[t * 20 + q] << pos;
        }
        if (((idx >> 4) & 255) == b) {
          int local = ((idx >> 16) & 15) * 256 + ((idx >> 12) & 15) * 16 +
                      (idx & 15);
          out[t] = s[PAD(local)];
        }
      }
    } else {
      int f0 = t * 4, f1 = (512 + t) * 4;
      int a0 = (f0 >> 8) * 65536 + ((f0 >> 4) & 15) * 4096 + b * 16 + (f0 & 15);
      int a1 = (f1 >> 8) * 65536 + ((f1 >> 4) & 15) * 4096 + b * 16 + (f1 & 15);
      cohstore(psi + a0, *(const v4f*)(s + PAD(f0)));
      cohstore(psi + a1, *(const v4f*)(s + PAD(f1)));
      gridbar(cnt, ++gen);
    }
  }
}

// ---------------------------------------------------------------------------
extern "C" void kernel_launch(void* const* d_in, const int* in_sizes, int n_in,
                              void* d_out, int out_size, void* d_ws, size_t ws_size,
                              hipStream_t stream) {
  const int* x = (const int*)d_in[0];
  const float* peps = (const float*)d_in[1];
  const float* gate = (const float*)d_in[2];
  float* ws = (float*)d_ws;
  float* out = (float*)d_out;
  int* cnt = (int*)(ws + CNTO);

  // zero the barrier tree (graph-capturable async memset node; its dispatch
  // end-release flushes the zeros to the coherent point for our atomics)
  hipMemsetAsync((void*)cnt, 0, 1088 * sizeof(int), stream);

  k_all<<<256, 512, 0, stream>>>(peps, x, gate, ws, out, cnt);
}